// Round 1
// baseline (1999.795 us; speedup 1.0000x reference)
//
#include <hip/hip_runtime.h>
#include <hip/hip_bf16.h>

typedef unsigned short u16;
typedef unsigned int u32;
typedef __bf16 bf16x8 __attribute__((ext_vector_type(8)));
typedef float f32x4 __attribute__((ext_vector_type(4)));

#define GF_BIAS 1
#define GF_BF16 2
#define GF_TRANS 4

#define MFMA16(a, b, c) __builtin_amdgcn_mfma_f32_16x16x32_bf16(a, b, c, 0, 0, 0)

static __device__ __forceinline__ u16 f2b(float f) {
  u32 u = __float_as_uint(f);
  return (u16)((u + 0x7FFFu + ((u >> 16) & 1u)) >> 16);
}

// ---------------- degree / norm ----------------
__global__ void deg_kernel(const int* __restrict__ dst, float* __restrict__ deg, int E) {
  int e = blockIdx.x * 256 + threadIdx.x;
  if (e < E) unsafeAtomicAdd(&deg[dst[e]], 1.0f);
}

__global__ void dis_kernel(float* __restrict__ d, int N) {
  int i = blockIdx.x * 256 + threadIdx.x;
  if (i < N) d[i] = rsqrtf(d[i] + 1.0f);  // +1 = self loop
}

// ---------------- fp32 SGEMM: C[M,Nn] = A[M,K] @ B[K,Nn] ----------------
__global__ __launch_bounds__(256) void sgemm(
    const float* __restrict__ A, const float* __restrict__ B,
    const float* __restrict__ bias, void* __restrict__ Cout,
    int M, int K, int Nn, int flags, float oscale, int ldt)
{
  __shared__ float As[32][68];  // [k][m], padded: store conflicts <= 2-way after +4 pad
  __shared__ float Bs[32][64];  // [k][n]
  int tid = threadIdx.x;
  int bm = blockIdx.x * 64, bn = blockIdx.y * 64;
  int tx = tid & 15, ty = tid >> 4;
  float acc[4][4] = {{0.f}};
  int ar = tid >> 3, ac = (tid & 7) * 4;
  int br = tid >> 4, bc = (tid & 15) * 4;
  for (int k0 = 0; k0 < K; k0 += 32) {
#pragma unroll
    for (int i = 0; i < 2; i++) {
      int r = ar + i * 32;
      float4 a = make_float4(0.f, 0.f, 0.f, 0.f);
      if (bm + r < M) a = *(const float4*)&A[(size_t)(bm + r) * K + k0 + ac];
      As[ac + 0][r] = a.x; As[ac + 1][r] = a.y;
      As[ac + 2][r] = a.z; As[ac + 3][r] = a.w;
    }
#pragma unroll
    for (int i = 0; i < 2; i++) {
      int r = br + i * 16;
      *(float4*)&Bs[r][bc] = *(const float4*)&B[(size_t)(k0 + r) * Nn + bn + bc];
    }
    __syncthreads();
#pragma unroll
    for (int kk = 0; kk < 32; kk++) {
      float4 av = *(const float4*)&As[kk][ty * 4];
      float4 bv = *(const float4*)&Bs[kk][tx * 4];
      acc[0][0] += av.x * bv.x; acc[0][1] += av.x * bv.y; acc[0][2] += av.x * bv.z; acc[0][3] += av.x * bv.w;
      acc[1][0] += av.y * bv.x; acc[1][1] += av.y * bv.y; acc[1][2] += av.y * bv.z; acc[1][3] += av.y * bv.w;
      acc[2][0] += av.z * bv.x; acc[2][1] += av.z * bv.y; acc[2][2] += av.z * bv.z; acc[2][3] += av.z * bv.w;
      acc[3][0] += av.w * bv.x; acc[3][1] += av.w * bv.y; acc[3][2] += av.w * bv.z; acc[3][3] += av.w * bv.w;
    }
    __syncthreads();
  }
#pragma unroll
  for (int i = 0; i < 4; i++) {
    int row = bm + ty * 4 + i;
    if (row >= M) continue;
#pragma unroll
    for (int j = 0; j < 4; j++) {
      int c = bn + tx * 4 + j;
      float v = acc[i][j];
      if (flags & GF_BIAS) v += bias[c];
      v *= oscale;
      if (flags & GF_BF16) {
        u16 hb = f2b(v);
        if (flags & GF_TRANS) ((u16*)Cout)[(size_t)c * ldt + row] = hb;
        else                  ((u16*)Cout)[(size_t)row * Nn + c] = hb;
      } else {
        ((float*)Cout)[(size_t)row * Nn + c] = v;
      }
    }
  }
}

// ---------------- edge scatter: agg[d] += h[s] * dis[s]*dis[d] ----------------
__global__ __launch_bounds__(256) void scatter_kernel(
    const float* __restrict__ h, const float* __restrict__ dis,
    const int* __restrict__ src, const int* __restrict__ dst,
    float* __restrict__ agg, int E)
{
  int t = blockIdx.x * 256 + threadIdx.x;
  int e = t >> 5;
  if (e >= E) return;
  int p = (t & 31) << 2;
  int s = src[e], d = dst[e];
  float w = dis[s] * dis[d];
  float4 hv = *(const float4*)&h[(size_t)s * 128 + p];
  float* a = &agg[(size_t)d * 128 + p];
  unsafeAtomicAdd(a + 0, hv.x * w);
  unsafeAtomicAdd(a + 1, hv.y * w);
  unsafeAtomicAdd(a + 2, hv.z * w);
  unsafeAtomicAdd(a + 3, hv.w * w);
}

// ---------------- self-loop + bias + LayerNorm (+optional SiLU), wave per row ----------------
__global__ __launch_bounds__(256) void postagg_kernel(
    const float* __restrict__ agg, const float* __restrict__ h,
    const float* __restrict__ dis, const float* __restrict__ bias,
    const float* __restrict__ g, const float* __restrict__ beta,
    float* __restrict__ out, int N, int do_silu)
{
  int row = blockIdx.x * 4 + (threadIdx.x >> 6);
  int lane = threadIdx.x & 63;
  if (row >= N) return;
  float di = dis[row];
  float sl = di * di;
  size_t base = (size_t)row * 128;
  float v0 = agg[base + lane]      + h[base + lane]      * sl + bias[lane];
  float v1 = agg[base + 64 + lane] + h[base + 64 + lane] * sl + bias[64 + lane];
  float s = v0 + v1;
#pragma unroll
  for (int d = 32; d > 0; d >>= 1) s += __shfl_xor(s, d, 64);
  float mu = s * (1.0f / 128.0f);
  float d0 = v0 - mu, d1 = v1 - mu;
  float q = d0 * d0 + d1 * d1;
#pragma unroll
  for (int d = 32; d > 0; d >>= 1) q += __shfl_xor(q, d, 64);
  float rstd = rsqrtf(q * (1.0f / 128.0f) + 1e-5f);
  float o0 = d0 * rstd * g[lane]      + beta[lane];
  float o1 = d1 * rstd * g[64 + lane] + beta[64 + lane];
  if (do_silu) {
    o0 = o0 / (1.f + __expf(-o0));
    o1 = o1 / (1.f + __expf(-o1));
  }
  out[base + lane] = o0;
  out[base + 64 + lane] = o1;
}

// ---------------- flash attention, 1 wave = 16 q rows, bf16 MFMA ----------------
// qb: [N,128] bf16 pre-scaled by 1/sqrt(128); kb: [NP,128] bf16 (pad rows zero);
// vt: [128,NP] bf16 transposed (pad keys zero). Epilogue fuses +out2 +ident, silu.
__global__ __launch_bounds__(64) void flash_attn(
    const u16* __restrict__ qb, const u16* __restrict__ kb,
    const u16* __restrict__ vt, const float* __restrict__ out2,
    const float* __restrict__ ident, float* __restrict__ out,
    int N, int NP)
{
  __shared__ u16 Pl[512];  // 16 rows x 32 keys bf16 (one wave per block)
  int lane = threadIdx.x;
  int col = lane & 15, quad = lane >> 4;
  int qbase = blockIdx.x * 16;
  // A-frag rows: m = lane&15
  int qr = qbase + col; if (qr > N - 1) qr = N - 1;
  const u16* qp = qb + (size_t)qr * 128 + quad * 8;
  bf16x8 aQ0 = *(const bf16x8*)(qp);
  bf16x8 aQ1 = *(const bf16x8*)(qp + 32);
  bf16x8 aQ2 = *(const bf16x8*)(qp + 64);
  bf16x8 aQ3 = *(const bf16x8*)(qp + 96);
  f32x4 O[8];
#pragma unroll
  for (int i = 0; i < 8; i++) { O[i][0] = 0.f; O[i][1] = 0.f; O[i][2] = 0.f; O[i][3] = 0.f; }
  float mr[4] = {-1e30f, -1e30f, -1e30f, -1e30f};
  float lr[4] = {0.f, 0.f, 0.f, 0.f};
  int KT = NP >> 5;
  for (int kt = 0; kt < KT; kt++) {
    int k0 = kt << 5;
    // S = Q @ K^T for 32 keys (two 16-col subtiles); B-frag: n=lane&15 (key), k=quad*8+j (ch)
    const u16* kp0 = kb + (size_t)(k0 + col) * 128 + quad * 8;
    const u16* kp1 = kp0 + 16 * 128;
    f32x4 S0; S0[0] = 0.f; S0[1] = 0.f; S0[2] = 0.f; S0[3] = 0.f;
    f32x4 S1 = S0;
    S0 = MFMA16(aQ0, *(const bf16x8*)(kp0),      S0);
    S0 = MFMA16(aQ1, *(const bf16x8*)(kp0 + 32), S0);
    S0 = MFMA16(aQ2, *(const bf16x8*)(kp0 + 64), S0);
    S0 = MFMA16(aQ3, *(const bf16x8*)(kp0 + 96), S0);
    S1 = MFMA16(aQ0, *(const bf16x8*)(kp1),      S1);
    S1 = MFMA16(aQ1, *(const bf16x8*)(kp1 + 32), S1);
    S1 = MFMA16(aQ2, *(const bf16x8*)(kp1 + 64), S1);
    S1 = MFMA16(aQ3, *(const bf16x8*)(kp1 + 96), S1);
    // mask padded keys (this lane's key column)
    if (k0 + col >= N)      { S0[0] = -1e30f; S0[1] = -1e30f; S0[2] = -1e30f; S0[3] = -1e30f; }
    if (k0 + 16 + col >= N) { S1[0] = -1e30f; S1[1] = -1e30f; S1[2] = -1e30f; S1[3] = -1e30f; }
    // online softmax; reg r <-> row quad*4+r; row stats via 16-lane butterfly
    float tm[4], ts[4], al[4];
#pragma unroll
    for (int r = 0; r < 4; r++) tm[r] = fmaxf(S0[r], S1[r]);
#pragma unroll
    for (int d = 1; d < 16; d <<= 1) {
#pragma unroll
      for (int r = 0; r < 4; r++) tm[r] = fmaxf(tm[r], __shfl_xor(tm[r], d, 64));
    }
    f32x4 P0, P1;
#pragma unroll
    for (int r = 0; r < 4; r++) {
      float mn = fmaxf(mr[r], tm[r]);
      al[r] = __expf(mr[r] - mn);
      mr[r] = mn;
      P0[r] = __expf(S0[r] - mn);
      P1[r] = __expf(S1[r] - mn);
      ts[r] = P0[r] + P1[r];
    }
#pragma unroll
    for (int d = 1; d < 16; d <<= 1) {
#pragma unroll
      for (int r = 0; r < 4; r++) ts[r] += __shfl_xor(ts[r], d, 64);
    }
#pragma unroll
    for (int r = 0; r < 4; r++) lr[r] = lr[r] * al[r] + ts[r];
#pragma unroll
    for (int nb = 0; nb < 8; nb++) {
      O[nb][0] *= al[0]; O[nb][1] *= al[1]; O[nb][2] *= al[2]; O[nb][3] *= al[3];
    }
    // P: C-layout -> A-layout via LDS (guide m120 pattern)
    __syncthreads();
    int wb = quad * 128 + col;  // (quad*4+r)*32 + sub*16 + col
    Pl[wb]       = f2b(P0[0]); Pl[wb + 16]  = f2b(P1[0]);
    Pl[wb + 32]  = f2b(P0[1]); Pl[wb + 48]  = f2b(P1[1]);
    Pl[wb + 64]  = f2b(P0[2]); Pl[wb + 80]  = f2b(P1[2]);
    Pl[wb + 96]  = f2b(P0[3]); Pl[wb + 112] = f2b(P1[3]);
    __syncthreads();
    bf16x8 aP = *(const bf16x8*)&Pl[col * 32 + quad * 8];
    // O += P @ V ; B-frag for V: n=lane&15 (ch), k=quad*8+j (key) -> vt[ch][key] contiguous
#pragma unroll
    for (int nb = 0; nb < 8; nb++) {
      const u16* vp = vt + (size_t)(nb * 16 + col) * NP + k0 + quad * 8;
      O[nb] = MFMA16(aP, *(const bf16x8*)vp, O[nb]);
    }
  }
  float il[4];
#pragma unroll
  for (int r = 0; r < 4; r++) il[r] = 1.0f / lr[r];
#pragma unroll
  for (int nb = 0; nb < 8; nb++) {
    int ch = nb * 16 + col;
#pragma unroll
    for (int r = 0; r < 4; r++) {
      int row = qbase + quad * 4 + r;
      if (row < N) {
        size_t idx = (size_t)row * 128 + ch;
        float val = O[nb][r] * il[r] + out2[idx] + ident[idx];
        out[idx] = val / (1.f + __expf(-val));  // silu
      }
    }
  }
}

extern "C" void kernel_launch(void* const* d_in, const int* in_sizes, int n_in,
                              void* d_out, int out_size, void* d_ws, size_t ws_size,
                              hipStream_t stream) {
  const float* x   = (const float*)d_in[0];
  const int*   ei  = (const int*)d_in[1];
  const float* W1  = (const float*)d_in[2];
  const float* b1  = (const float*)d_in[3];
  const float* W2  = (const float*)d_in[4];
  const float* b2  = (const float*)d_in[5];
  const float* g1  = (const float*)d_in[6];
  const float* be1 = (const float*)d_in[7];
  const float* g2  = (const float*)d_in[8];
  const float* be2 = (const float*)d_in[9];
  const float* Wq  = (const float*)d_in[10];
  const float* bq  = (const float*)d_in[11];
  const float* Wk  = (const float*)d_in[12];
  const float* bk  = (const float*)d_in[13];
  const float* Wv  = (const float*)d_in[14];
  const float* bv  = (const float*)d_in[15];
  const float* Wsw = (const float*)d_in[16];
  const float* bs  = (const float*)d_in[17];

  const int CIN = 256, C = 128;
  int N = in_sizes[0] / CIN;
  int E = in_sizes[1] / 2;
  int NP = (N + 31) & ~31;
  const int* src = ei;
  const int* dstp = ei + E;

  char* w = (char*)d_ws;
  size_t off = 0;
  auto alloc = [&](size_t bytes) -> void* {
    void* p = w + off;
    off = (off + bytes + 255) & ~(size_t)255;
    return p;
  };
  float* disb  = (float*)alloc((size_t)N * 4);
  float* h     = (float*)alloc((size_t)N * C * 4);
  float* ident = (float*)alloc((size_t)N * C * 4);
  float* agg   = (float*)alloc((size_t)N * C * 4);
  float* cur   = (float*)alloc((size_t)N * C * 4);
  u16*   qb    = (u16*)alloc((size_t)N * C * 2);
  u16*   kbb   = (u16*)alloc((size_t)NP * C * 2);
  u16*   vt    = (u16*)alloc((size_t)C * NP * 2);

  hipMemsetAsync(disb, 0, (size_t)N * 4, stream);
  hipMemsetAsync(agg, 0, (size_t)N * C * 4, stream);
  hipMemsetAsync(kbb, 0, (size_t)NP * C * 2, stream);
  hipMemsetAsync(vt, 0, (size_t)C * NP * 2, stream);

  deg_kernel<<<(E + 255) / 256, 256, 0, stream>>>(dstp, disb, E);
  dis_kernel<<<(N + 255) / 256, 256, 0, stream>>>(disb, N);

  dim3 gg((N + 63) / 64, C / 64);
  // h1 = x @ W1  (bias after aggregation)
  sgemm<<<gg, 256, 0, stream>>>(x, W1, nullptr, h, N, CIN, C, 0, 1.f, 0);
  // identity = x @ Ws + bs
  sgemm<<<gg, 256, 0, stream>>>(x, Wsw, bs, ident, N, CIN, C, GF_BIAS, 1.f, 0);
  scatter_kernel<<<(E * 32 + 255) / 256, 256, 0, stream>>>(h, disb, src, dstp, agg, E);
  // out1 = silu(LN1(agg + self + b1))
  postagg_kernel<<<(N + 3) / 4, 256, 0, stream>>>(agg, h, disb, b1, g1, be1, cur, N, 1);
  hipMemsetAsync(agg, 0, (size_t)N * C * 4, stream);
  // h2 = out1 @ W2
  sgemm<<<gg, 256, 0, stream>>>(cur, W2, nullptr, h, N, C, C, 0, 1.f, 0);
  scatter_kernel<<<(E * 32 + 255) / 256, 256, 0, stream>>>(h, disb, src, dstp, agg, E);
  // out2 = LN2(agg + self + b2)
  postagg_kernel<<<(N + 3) / 4, 256, 0, stream>>>(agg, h, disb, b2, g2, be2, cur, N, 0);

  const float qscale = 0.08838834764831845f;  // 1/sqrt(128)
  sgemm<<<gg, 256, 0, stream>>>(cur, Wq, bq, qb, N, C, C, GF_BIAS | GF_BF16, qscale, 0);
  sgemm<<<gg, 256, 0, stream>>>(cur, Wk, bk, kbb, N, C, C, GF_BIAS | GF_BF16, 1.f, 0);
  sgemm<<<gg, 256, 0, stream>>>(cur, Wv, bv, vt, N, C, C, GF_BIAS | GF_BF16 | GF_TRANS, 1.f, NP);

  flash_attn<<<(N + 15) / 16, 64, 0, stream>>>(qb, kbb, vt, cur, ident, (float*)d_out, N, NP);
}

// Round 2
// 662.538 us; speedup vs baseline: 3.0184x; 3.0184x over previous
//
#include <hip/hip_runtime.h>
#include <hip/hip_bf16.h>

typedef unsigned short u16;
typedef unsigned int u32;
typedef __bf16 bf16x8 __attribute__((ext_vector_type(8)));
typedef float f32x4 __attribute__((ext_vector_type(4)));

#define GF_BIAS 1
#define GF_BF16 2
#define GF_TRANS 4

#define MFMA16(a, b, c) __builtin_amdgcn_mfma_f32_16x16x32_bf16(a, b, c, 0, 0, 0)

static __device__ __forceinline__ u16 f2b(float f) {
  u32 u = __float_as_uint(f);
  return (u16)((u + 0x7FFFu + ((u >> 16) & 1u)) >> 16);
}

// ---------------- CSR build ----------------
__global__ void degi_kernel(const int* __restrict__ dst, int* __restrict__ degi, int E) {
  int e = blockIdx.x * 256 + threadIdx.x;
  if (e < E) atomicAdd(&degi[dst[e]], 1);
}

__global__ void dis_kernel(const int* __restrict__ degi, float* __restrict__ d, int N) {
  int i = blockIdx.x * 256 + threadIdx.x;
  if (i < N) d[i] = rsqrtf((float)degi[i] + 1.0f);  // +1 = self loop
}

// Disjoint CSR ranges via atomic bump; order across nodes irrelevant.
__global__ void start_kernel(const int* __restrict__ degi, int* __restrict__ startb,
                             int* __restrict__ counter, int N) {
  int i = blockIdx.x * 256 + threadIdx.x;
  if (i < N) startb[i] = atomicAdd(counter, degi[i]);
}

__global__ void fill_kernel(const int* __restrict__ src, const int* __restrict__ dst,
                            const int* __restrict__ startb, int* __restrict__ cursor,
                            int* __restrict__ adj, int E) {
  int e = blockIdx.x * 256 + threadIdx.x;
  if (e < E) {
    int d = dst[e];
    int p = atomicAdd(&cursor[d], 1);
    adj[startb[d] + p] = src[e];
  }
}

// ---------------- fp32 SGEMM: C[M,Nn] = A[M,K] @ B[K,Nn] ----------------
__global__ __launch_bounds__(256) void sgemm(
    const float* __restrict__ A, const float* __restrict__ B,
    const float* __restrict__ bias, void* __restrict__ Cout,
    int M, int K, int Nn, int flags, float oscale, int ldt)
{
  __shared__ float As[32][68];
  __shared__ float Bs[32][64];
  int tid = threadIdx.x;
  int bm = blockIdx.x * 64, bn = blockIdx.y * 64;
  int tx = tid & 15, ty = tid >> 4;
  float acc[4][4] = {{0.f}};
  int ar = tid >> 3, ac = (tid & 7) * 4;
  int br = tid >> 4, bc = (tid & 15) * 4;
  for (int k0 = 0; k0 < K; k0 += 32) {
#pragma unroll
    for (int i = 0; i < 2; i++) {
      int r = ar + i * 32;
      float4 a = make_float4(0.f, 0.f, 0.f, 0.f);
      if (bm + r < M) a = *(const float4*)&A[(size_t)(bm + r) * K + k0 + ac];
      As[ac + 0][r] = a.x; As[ac + 1][r] = a.y;
      As[ac + 2][r] = a.z; As[ac + 3][r] = a.w;
    }
#pragma unroll
    for (int i = 0; i < 2; i++) {
      int r = br + i * 16;
      *(float4*)&Bs[r][bc] = *(const float4*)&B[(size_t)(k0 + r) * Nn + bn + bc];
    }
    __syncthreads();
#pragma unroll
    for (int kk = 0; kk < 32; kk++) {
      float4 av = *(const float4*)&As[kk][ty * 4];
      float4 bv = *(const float4*)&Bs[kk][tx * 4];
      acc[0][0] += av.x * bv.x; acc[0][1] += av.x * bv.y; acc[0][2] += av.x * bv.z; acc[0][3] += av.x * bv.w;
      acc[1][0] += av.y * bv.x; acc[1][1] += av.y * bv.y; acc[1][2] += av.y * bv.z; acc[1][3] += av.y * bv.w;
      acc[2][0] += av.z * bv.x; acc[2][1] += av.z * bv.y; acc[2][2] += av.z * bv.z; acc[2][3] += av.z * bv.w;
      acc[3][0] += av.w * bv.x; acc[3][1] += av.w * bv.y; acc[3][2] += av.w * bv.z; acc[3][3] += av.w * bv.w;
    }
    __syncthreads();
  }
#pragma unroll
  for (int i = 0; i < 4; i++) {
    int row = bm + ty * 4 + i;
    if (row >= M) continue;
#pragma unroll
    for (int j = 0; j < 4; j++) {
      int c = bn + tx * 4 + j;
      float v = acc[i][j];
      if (flags & GF_BIAS) v += bias[c];
      v *= oscale;
      if (flags & GF_BF16) {
        u16 hb = f2b(v);
        if (flags & GF_TRANS) ((u16*)Cout)[(size_t)c * ldt + row] = hb;
        else                  ((u16*)Cout)[(size_t)row * Nn + c] = hb;
      } else {
        ((float*)Cout)[(size_t)row * Nn + c] = v;
      }
    }
  }
}

// ---------------- fused CSR gather + self-loop + bias + LN (+SiLU), wave per row ----------------
// out_row = LN( dis[d]*(sum_s dis[s]*h[s] + dis[d]*h[d]) + bias ) [*silu]
__global__ __launch_bounds__(256) void gather_ln(
    const float* __restrict__ h, const float* __restrict__ dis,
    const int* __restrict__ adj, const int* __restrict__ startb, const int* __restrict__ degi,
    const float* __restrict__ bias, const float* __restrict__ g, const float* __restrict__ beta,
    float* __restrict__ out, int N, int do_silu)
{
  int row = blockIdx.x * 4 + (threadIdx.x >> 6);
  int lane = threadIdx.x & 63;
  if (row >= N) return;
  int st = startb[row], dg = degi[row];
  float v0 = 0.f, v1 = 0.f;
  for (int base = 0; base < dg; base += 64) {
    int nb = min(64, dg - base);
    int myadj = 0; float mydis = 0.f;
    if (lane < nb) { myadj = adj[st + base + lane]; mydis = dis[myadj]; }
    int jj = 0;
    for (; jj + 4 <= nb; jj += 4) {
      int s0 = __shfl(myadj, jj), s1 = __shfl(myadj, jj + 1);
      int s2 = __shfl(myadj, jj + 2), s3 = __shfl(myadj, jj + 3);
      float w0 = __shfl(mydis, jj), w1 = __shfl(mydis, jj + 1);
      float w2 = __shfl(mydis, jj + 2), w3 = __shfl(mydis, jj + 3);
      const float* p0 = &h[(size_t)s0 * 128 + lane];
      const float* p1 = &h[(size_t)s1 * 128 + lane];
      const float* p2 = &h[(size_t)s2 * 128 + lane];
      const float* p3 = &h[(size_t)s3 * 128 + lane];
      v0 += w0 * p0[0]; v1 += w0 * p0[64];
      v0 += w1 * p1[0]; v1 += w1 * p1[64];
      v0 += w2 * p2[0]; v1 += w2 * p2[64];
      v0 += w3 * p3[0]; v1 += w3 * p3[64];
    }
    for (; jj < nb; jj++) {
      int s = __shfl(myadj, jj);
      float wv = __shfl(mydis, jj);
      const float* p = &h[(size_t)s * 128 + lane];
      v0 += wv * p[0]; v1 += wv * p[64];
    }
  }
  float dd = dis[row];
  const float* hp = &h[(size_t)row * 128 + lane];
  v0 = (v0 + dd * hp[0])  * dd + bias[lane];
  v1 = (v1 + dd * hp[64]) * dd + bias[64 + lane];
  float s = v0 + v1;
#pragma unroll
  for (int d = 32; d > 0; d >>= 1) s += __shfl_xor(s, d, 64);
  float mu = s * (1.0f / 128.0f);
  float d0 = v0 - mu, d1 = v1 - mu;
  float q = d0 * d0 + d1 * d1;
#pragma unroll
  for (int d = 32; d > 0; d >>= 1) q += __shfl_xor(q, d, 64);
  float rstd = rsqrtf(q * (1.0f / 128.0f) + 1e-5f);
  float o0 = d0 * rstd * g[lane]      + beta[lane];
  float o1 = d1 * rstd * g[64 + lane] + beta[64 + lane];
  if (do_silu) {
    o0 = o0 / (1.f + __expf(-o0));
    o1 = o1 / (1.f + __expf(-o1));
  }
  size_t base = (size_t)row * 128;
  out[base + lane] = o0;
  out[base + 64 + lane] = o1;
}

// ---------------- flash attention: 4 waves/block K-split one 16-row Q tile ----------------
// qb pre-scaled by 1/sqrt(128); kb [NP,128] (pad rows zero); vt [128,NP] (pad cols zero).
// Wave w handles key tiles kt = w, w+4, ... Partials combined in LDS at block end.
__global__ __launch_bounds__(256) void flash_attn4(
    const u16* __restrict__ qb, const u16* __restrict__ kb,
    const u16* __restrict__ vt, const float* __restrict__ out2,
    const float* __restrict__ ident, float* __restrict__ out,
    int N, int NP)
{
  __shared__ float Ow[4][16][128];
  __shared__ u16 Pl[4][512];
  __shared__ float mw[4][16], lw[4][16], wws[4][16], winv[16];
  int tid = threadIdx.x;
  int w = tid >> 6, lane = tid & 63;
  int col = lane & 15, quad = lane >> 4;
  int qbase = blockIdx.x * 16;
  int qr = qbase + col; if (qr > N - 1) qr = N - 1;
  const u16* qp = qb + (size_t)qr * 128 + quad * 8;
  bf16x8 aQ0 = *(const bf16x8*)(qp);
  bf16x8 aQ1 = *(const bf16x8*)(qp + 32);
  bf16x8 aQ2 = *(const bf16x8*)(qp + 64);
  bf16x8 aQ3 = *(const bf16x8*)(qp + 96);
  f32x4 O[8];
#pragma unroll
  for (int i = 0; i < 8; i++) { O[i][0] = 0.f; O[i][1] = 0.f; O[i][2] = 0.f; O[i][3] = 0.f; }
  float mr[4] = {-1e30f, -1e30f, -1e30f, -1e30f};
  float lr[4] = {0.f, 0.f, 0.f, 0.f};
  int KT = NP >> 5;
  for (int kt = w; kt < KT; kt += 4) {
    int k0 = kt << 5;
    const u16* kp0 = kb + (size_t)(k0 + col) * 128 + quad * 8;
    const u16* kp1 = kp0 + 16 * 128;
    f32x4 S0; S0[0] = 0.f; S0[1] = 0.f; S0[2] = 0.f; S0[3] = 0.f;
    f32x4 S1 = S0;
    S0 = MFMA16(aQ0, *(const bf16x8*)(kp0),      S0);
    S0 = MFMA16(aQ1, *(const bf16x8*)(kp0 + 32), S0);
    S0 = MFMA16(aQ2, *(const bf16x8*)(kp0 + 64), S0);
    S0 = MFMA16(aQ3, *(const bf16x8*)(kp0 + 96), S0);
    S1 = MFMA16(aQ0, *(const bf16x8*)(kp1),      S1);
    S1 = MFMA16(aQ1, *(const bf16x8*)(kp1 + 32), S1);
    S1 = MFMA16(aQ2, *(const bf16x8*)(kp1 + 64), S1);
    S1 = MFMA16(aQ3, *(const bf16x8*)(kp1 + 96), S1);
    if (k0 + col >= N)      { S0[0] = -1e30f; S0[1] = -1e30f; S0[2] = -1e30f; S0[3] = -1e30f; }
    if (k0 + 16 + col >= N) { S1[0] = -1e30f; S1[1] = -1e30f; S1[2] = -1e30f; S1[3] = -1e30f; }
    float tm[4], ts[4], al[4];
#pragma unroll
    for (int r = 0; r < 4; r++) tm[r] = fmaxf(S0[r], S1[r]);
#pragma unroll
    for (int d = 1; d < 16; d <<= 1) {
#pragma unroll
      for (int r = 0; r < 4; r++) tm[r] = fmaxf(tm[r], __shfl_xor(tm[r], d, 64));
    }
    f32x4 P0, P1;
#pragma unroll
    for (int r = 0; r < 4; r++) {
      float mn = fmaxf(mr[r], tm[r]);
      al[r] = __expf(mr[r] - mn);
      mr[r] = mn;
      P0[r] = __expf(S0[r] - mn);
      P1[r] = __expf(S1[r] - mn);
      ts[r] = P0[r] + P1[r];
    }
#pragma unroll
    for (int d = 1; d < 16; d <<= 1) {
#pragma unroll
      for (int r = 0; r < 4; r++) ts[r] += __shfl_xor(ts[r], d, 64);
    }
#pragma unroll
    for (int r = 0; r < 4; r++) lr[r] = lr[r] * al[r] + ts[r];
#pragma unroll
    for (int nb = 0; nb < 8; nb++) {
      O[nb][0] *= al[0]; O[nb][1] *= al[1]; O[nb][2] *= al[2]; O[nb][3] *= al[3];
    }
    // P: C-layout -> A-layout via wave-private LDS (DS ops are in-order per wave;
    // the waitcnt+clobber pins compiler ordering). No block barrier: trip counts differ per wave.
    u16* pl = &Pl[w][0];
    int wb = quad * 128 + col;
    pl[wb]       = f2b(P0[0]); pl[wb + 16]  = f2b(P1[0]);
    pl[wb + 32]  = f2b(P0[1]); pl[wb + 48]  = f2b(P1[1]);
    pl[wb + 64]  = f2b(P0[2]); pl[wb + 80]  = f2b(P1[2]);
    pl[wb + 96]  = f2b(P0[3]); pl[wb + 112] = f2b(P1[3]);
    asm volatile("s_waitcnt lgkmcnt(0)" ::: "memory");
    bf16x8 aP = *(const bf16x8*)&pl[col * 32 + quad * 8];
#pragma unroll
    for (int nb = 0; nb < 8; nb++) {
      const u16* vp = vt + (size_t)(nb * 16 + col) * NP + k0 + quad * 8;
      O[nb] = MFMA16(aP, *(const bf16x8*)vp, O[nb]);
    }
  }
  // dump per-wave partials
#pragma unroll
  for (int nb = 0; nb < 8; nb++) {
#pragma unroll
    for (int r = 0; r < 4; r++) Ow[w][quad * 4 + r][nb * 16 + col] = O[nb][r];
  }
  if (col == 0) {
#pragma unroll
    for (int r = 0; r < 4; r++) { mw[w][quad * 4 + r] = mr[r]; lw[w][quad * 4 + r] = lr[r]; }
  }
  __syncthreads();
  if (tid < 16) {
    float ms = fmaxf(fmaxf(mw[0][tid], mw[1][tid]), fmaxf(mw[2][tid], mw[3][tid]));
    float lt = 0.f;
#pragma unroll
    for (int u = 0; u < 4; u++) {
      float e = __expf(mw[u][tid] - ms);
      wws[u][tid] = e;
      lt += e * lw[u][tid];
    }
    winv[tid] = 1.0f / lt;
  }
  __syncthreads();
  for (int i = tid; i < 2048; i += 256) {
    int row = i >> 7, ch = i & 127;
    int gr = qbase + row;
    if (gr >= N) continue;
    float val = wws[0][row] * Ow[0][row][ch] + wws[1][row] * Ow[1][row][ch]
              + wws[2][row] * Ow[2][row][ch] + wws[3][row] * Ow[3][row][ch];
    size_t idx = (size_t)gr * 128 + ch;
    float v = val * winv[row] + out2[idx] + ident[idx];
    out[idx] = v / (1.f + __expf(-v));
  }
}

extern "C" void kernel_launch(void* const* d_in, const int* in_sizes, int n_in,
                              void* d_out, int out_size, void* d_ws, size_t ws_size,
                              hipStream_t stream) {
  const float* x   = (const float*)d_in[0];
  const int*   ei  = (const int*)d_in[1];
  const float* W1  = (const float*)d_in[2];
  const float* b1  = (const float*)d_in[3];
  const float* W2  = (const float*)d_in[4];
  const float* b2  = (const float*)d_in[5];
  const float* g1  = (const float*)d_in[6];
  const float* be1 = (const float*)d_in[7];
  const float* g2  = (const float*)d_in[8];
  const float* be2 = (const float*)d_in[9];
  const float* Wq  = (const float*)d_in[10];
  const float* bq  = (const float*)d_in[11];
  const float* Wk  = (const float*)d_in[12];
  const float* bk  = (const float*)d_in[13];
  const float* Wv  = (const float*)d_in[14];
  const float* bv  = (const float*)d_in[15];
  const float* Wsw = (const float*)d_in[16];
  const float* bs  = (const float*)d_in[17];

  const int CIN = 256, C = 128;
  int N = in_sizes[0] / CIN;
  int E = in_sizes[1] / 2;
  int NP = (N + 31) & ~31;
  const int* src = ei;
  const int* dstp = ei + E;

  char* w = (char*)d_ws;
  size_t off = 0;
  auto alloc = [&](size_t bytes) -> void* {
    void* p = w + off;
    off = (off + bytes + 255) & ~(size_t)255;
    return p;
  };
  float* disb   = (float*)alloc((size_t)N * 4);
  int*   degi   = (int*)alloc((size_t)N * 4);
  int*   startb = (int*)alloc((size_t)N * 4);
  int*   cursor = (int*)alloc((size_t)N * 4);
  int*   counter= (int*)alloc(256);
  int*   adj    = (int*)alloc((size_t)E * 4);
  float* h      = (float*)alloc((size_t)N * C * 4);
  float* ident  = (float*)alloc((size_t)N * C * 4);
  float* cur    = (float*)alloc((size_t)N * C * 4);
  u16*   qbb    = (u16*)alloc((size_t)N * C * 2);
  u16*   kbb    = (u16*)alloc((size_t)NP * C * 2);
  u16*   vt     = (u16*)alloc((size_t)C * NP * 2);

  hipMemsetAsync(degi, 0, (size_t)N * 4, stream);
  hipMemsetAsync(cursor, 0, (size_t)N * 4, stream);
  hipMemsetAsync(counter, 0, 256, stream);
  hipMemsetAsync(kbb, 0, (size_t)NP * C * 2, stream);
  hipMemsetAsync(vt, 0, (size_t)C * NP * 2, stream);

  int gE = (E + 255) / 256, gN = (N + 255) / 256;
  degi_kernel<<<gE, 256, 0, stream>>>(dstp, degi, E);
  dis_kernel<<<gN, 256, 0, stream>>>(degi, disb, N);
  start_kernel<<<gN, 256, 0, stream>>>(degi, startb, counter, N);
  fill_kernel<<<gE, 256, 0, stream>>>(src, dstp, startb, cursor, adj, E);

  dim3 gg((N + 63) / 64, C / 64);
  // h1 = x @ W1 (bias folded into gather_ln)
  sgemm<<<gg, 256, 0, stream>>>(x, W1, nullptr, h, N, CIN, C, 0, 1.f, 0);
  // identity = x @ Ws + bs
  sgemm<<<gg, 256, 0, stream>>>(x, Wsw, bs, ident, N, CIN, C, GF_BIAS, 1.f, 0);
  // out1 = silu(LN1(gather(h1) + b1))
  gather_ln<<<(N + 3) / 4, 256, 0, stream>>>(h, disb, adj, startb, degi, b1, g1, be1, cur, N, 1);
  // h2 = out1 @ W2
  sgemm<<<gg, 256, 0, stream>>>(cur, W2, nullptr, h, N, C, C, 0, 1.f, 0);
  // out2 = LN2(gather(h2) + b2)
  gather_ln<<<(N + 3) / 4, 256, 0, stream>>>(h, disb, adj, startb, degi, b2, g2, be2, cur, N, 0);

  const float qscale = 0.08838834764831845f;  // 1/sqrt(128)
  sgemm<<<gg, 256, 0, stream>>>(cur, Wq, bq, qbb, N, C, C, GF_BIAS | GF_BF16, qscale, 0);
  sgemm<<<gg, 256, 0, stream>>>(cur, Wk, bk, kbb, N, C, C, GF_BIAS | GF_BF16, 1.f, 0);
  sgemm<<<gg, 256, 0, stream>>>(cur, Wv, bv, vt, N, C, C, GF_BIAS | GF_BF16 | GF_TRANS, 1.f, NP);

  flash_attn4<<<(N + 15) / 16, 256, 0, stream>>>(qbb, kbb, vt, cur, ident, (float*)d_out, N, NP);
}

// Round 3
// 616.762 us; speedup vs baseline: 3.2424x; 1.0742x over previous
//
#include <hip/hip_runtime.h>
#include <hip/hip_bf16.h>

typedef unsigned short u16;
typedef unsigned int u32;
typedef __bf16 bf16x8 __attribute__((ext_vector_type(8)));
typedef float f32x4 __attribute__((ext_vector_type(4)));

#define GF_BIAS 1
#define GF_BF16 2
#define GF_TRANS 4

#define MFMA16(a, b, c) __builtin_amdgcn_mfma_f32_16x16x32_bf16(a, b, c, 0, 0, 0)

static __device__ __forceinline__ u16 f2b(float f) {
  u32 u = __float_as_uint(f);
  return (u16)((u + 0x7FFFu + ((u >> 16) & 1u)) >> 16);
}

// async 16B/lane global->LDS DMA; dst = uniform base + lane*16
static __device__ __forceinline__ void async_copy16(void* lds, const void* gp) {
  __builtin_amdgcn_global_load_lds(
      (const __attribute__((address_space(1))) unsigned int*)gp,
      (__attribute__((address_space(3))) unsigned int*)lds, 16, 0, 0);
}

// ---------------- CSR build ----------------
__global__ void degi_kernel(const int* __restrict__ dst, int* __restrict__ degi, int E) {
  int e = blockIdx.x * 256 + threadIdx.x;
  if (e < E) atomicAdd(&degi[dst[e]], 1);
}

__global__ void dis_kernel(const int* __restrict__ degi, float* __restrict__ d, int N) {
  int i = blockIdx.x * 256 + threadIdx.x;
  if (i < N) d[i] = rsqrtf((float)degi[i] + 1.0f);  // +1 = self loop
}

__global__ void start_kernel(const int* __restrict__ degi, int* __restrict__ startb,
                             int* __restrict__ counter, int N) {
  int i = blockIdx.x * 256 + threadIdx.x;
  if (i < N) startb[i] = atomicAdd(counter, degi[i]);
}

__global__ void fill_kernel(const int* __restrict__ src, const int* __restrict__ dst,
                            const int* __restrict__ startb, int* __restrict__ cursor,
                            int* __restrict__ adj, int E) {
  int e = blockIdx.x * 256 + threadIdx.x;
  if (e < E) {
    int d = dst[e];
    int p = atomicAdd(&cursor[d], 1);
    adj[startb[d] + p] = src[e];
  }
}

// ---------------- fp32 SGEMM: C[M,Nn] = A[M,K] @ B[K,Nn] ----------------
__global__ __launch_bounds__(256) void sgemm(
    const float* __restrict__ A, const float* __restrict__ B,
    const float* __restrict__ bias, void* __restrict__ Cout,
    int M, int K, int Nn, int flags, float oscale, int ldt)
{
  __shared__ float As[32][68];
  __shared__ float Bs[32][64];
  int tid = threadIdx.x;
  int bm = blockIdx.x * 64, bn = blockIdx.y * 64;
  int tx = tid & 15, ty = tid >> 4;
  float acc[4][4] = {{0.f}};
  int ar = tid >> 3, ac = (tid & 7) * 4;
  int br = tid >> 4, bc = (tid & 15) * 4;
  for (int k0 = 0; k0 < K; k0 += 32) {
#pragma unroll
    for (int i = 0; i < 2; i++) {
      int r = ar + i * 32;
      float4 a = make_float4(0.f, 0.f, 0.f, 0.f);
      if (bm + r < M) a = *(const float4*)&A[(size_t)(bm + r) * K + k0 + ac];
      As[ac + 0][r] = a.x; As[ac + 1][r] = a.y;
      As[ac + 2][r] = a.z; As[ac + 3][r] = a.w;
    }
#pragma unroll
    for (int i = 0; i < 2; i++) {
      int r = br + i * 16;
      *(float4*)&Bs[r][bc] = *(const float4*)&B[(size_t)(k0 + r) * Nn + bn + bc];
    }
    __syncthreads();
#pragma unroll
    for (int kk = 0; kk < 32; kk++) {
      float4 av = *(const float4*)&As[kk][ty * 4];
      float4 bv = *(const float4*)&Bs[kk][tx * 4];
      acc[0][0] += av.x * bv.x; acc[0][1] += av.x * bv.y; acc[0][2] += av.x * bv.z; acc[0][3] += av.x * bv.w;
      acc[1][0] += av.y * bv.x; acc[1][1] += av.y * bv.y; acc[1][2] += av.y * bv.z; acc[1][3] += av.y * bv.w;
      acc[2][0] += av.z * bv.x; acc[2][1] += av.z * bv.y; acc[2][2] += av.z * bv.z; acc[2][3] += av.z * bv.w;
      acc[3][0] += av.w * bv.x; acc[3][1] += av.w * bv.y; acc[3][2] += av.w * bv.z; acc[3][3] += av.w * bv.w;
    }
    __syncthreads();
  }
#pragma unroll
  for (int i = 0; i < 4; i++) {
    int row = bm + ty * 4 + i;
    if (row >= M) continue;
#pragma unroll
    for (int j = 0; j < 4; j++) {
      int c = bn + tx * 4 + j;
      float v = acc[i][j];
      if (flags & GF_BIAS) v += bias[c];
      v *= oscale;
      if (flags & GF_BF16) {
        u16 hb = f2b(v);
        if (flags & GF_TRANS) ((u16*)Cout)[(size_t)c * ldt + row] = hb;
        else                  ((u16*)Cout)[(size_t)row * Nn + c] = hb;
      } else {
        ((float*)Cout)[(size_t)row * Nn + c] = v;
      }
    }
  }
}

// ---------------- fused CSR gather + self-loop + bias + LN (+SiLU), wave per row ----------------
__global__ __launch_bounds__(256) void gather_ln(
    const float* __restrict__ h, const float* __restrict__ dis,
    const int* __restrict__ adj, const int* __restrict__ startb, const int* __restrict__ degi,
    const float* __restrict__ bias, const float* __restrict__ g, const float* __restrict__ beta,
    float* __restrict__ out, int N, int do_silu)
{
  int row = blockIdx.x * 4 + (threadIdx.x >> 6);
  int lane = threadIdx.x & 63;
  if (row >= N) return;
  int st = startb[row], dg = degi[row];
  float v0 = 0.f, v1 = 0.f;
  for (int base = 0; base < dg; base += 64) {
    int nb = min(64, dg - base);
    int myadj = 0; float mydis = 0.f;
    if (lane < nb) { myadj = adj[st + base + lane]; mydis = dis[myadj]; }
    int jj = 0;
    for (; jj + 4 <= nb; jj += 4) {
      int s0 = __shfl(myadj, jj), s1 = __shfl(myadj, jj + 1);
      int s2 = __shfl(myadj, jj + 2), s3 = __shfl(myadj, jj + 3);
      float w0 = __shfl(mydis, jj), w1 = __shfl(mydis, jj + 1);
      float w2 = __shfl(mydis, jj + 2), w3 = __shfl(mydis, jj + 3);
      const float* p0 = &h[(size_t)s0 * 128 + lane];
      const float* p1 = &h[(size_t)s1 * 128 + lane];
      const float* p2 = &h[(size_t)s2 * 128 + lane];
      const float* p3 = &h[(size_t)s3 * 128 + lane];
      v0 += w0 * p0[0]; v1 += w0 * p0[64];
      v0 += w1 * p1[0]; v1 += w1 * p1[64];
      v0 += w2 * p2[0]; v1 += w2 * p2[64];
      v0 += w3 * p3[0]; v1 += w3 * p3[64];
    }
    for (; jj < nb; jj++) {
      int s = __shfl(myadj, jj);
      float wv = __shfl(mydis, jj);
      const float* p = &h[(size_t)s * 128 + lane];
      v0 += wv * p[0]; v1 += wv * p[64];
    }
  }
  float dd = dis[row];
  const float* hp = &h[(size_t)row * 128 + lane];
  v0 = (v0 + dd * hp[0])  * dd + bias[lane];
  v1 = (v1 + dd * hp[64]) * dd + bias[64 + lane];
  float s = v0 + v1;
#pragma unroll
  for (int d = 32; d > 0; d >>= 1) s += __shfl_xor(s, d, 64);
  float mu = s * (1.0f / 128.0f);
  float d0 = v0 - mu, d1 = v1 - mu;
  float q = d0 * d0 + d1 * d1;
#pragma unroll
  for (int d = 32; d > 0; d >>= 1) q += __shfl_xor(q, d, 64);
  float rstd = rsqrtf(q * (1.0f / 128.0f) + 1e-5f);
  float o0 = d0 * rstd * g[lane]      + beta[lane];
  float o1 = d1 * rstd * g[64 + lane] + beta[64 + lane];
  if (do_silu) {
    o0 = o0 / (1.f + __expf(-o0));
    o1 = o1 / (1.f + __expf(-o1));
  }
  size_t base = (size_t)row * 128;
  out[base + lane] = o0;
  out[base + 64 + lane] = o1;
}

// ---------------- flash attention: Q-tile 64 (16 rows/wave), K/V tiles via LDS DMA ----------------
// K/V staged double-buffered with global_load_lds (16B). LDS layouts XOR-swizzled
// (chunk' = chunk ^ (row&7), 16B chunks) so ds_read_b128 frag reads are conflict-free.
// qb pre-scaled by 1/sqrt(128); kb [NP,128]; vt [128,NP]; NP mult of 64, pads zero.
__global__ __launch_bounds__(256) void flash_lds(
    const u16* __restrict__ qb, const u16* __restrict__ kb,
    const u16* __restrict__ vt, const float* __restrict__ out2,
    const float* __restrict__ ident, float* __restrict__ out,
    int N, int NP)
{
  __shared__ __align__(16) u16 Kl[2][64 * 128];   // [key][128ch], swizzled chunks
  __shared__ __align__(16) u16 Vl[2][128 * 64];   // [ch][64key], swizzled chunks
  __shared__ __align__(16) u16 Pl[4][16][72];     // per-wave P relayout, +8 pad
  int tid = threadIdx.x;
  int w = tid >> 6, lane = tid & 63;
  int col = lane & 15, quad = lane >> 4;
  int h8 = col & 7;
  int qbase = blockIdx.x * 64 + w * 16;  // this wave's 16 Q rows

  int qr = qbase + col; if (qr > N - 1) qr = N - 1;
  const u16* qp = qb + (size_t)qr * 128 + quad * 8;
  bf16x8 aQ[4];
  aQ[0] = *(const bf16x8*)(qp);
  aQ[1] = *(const bf16x8*)(qp + 32);
  aQ[2] = *(const bf16x8*)(qp + 64);
  aQ[3] = *(const bf16x8*)(qp + 96);

  f32x4 O[8];
#pragma unroll
  for (int i = 0; i < 8; i++) { O[i][0] = 0.f; O[i][1] = 0.f; O[i][2] = 0.f; O[i][3] = 0.f; }
  float mr[4] = {-1e30f, -1e30f, -1e30f, -1e30f};
  float lr[4] = {0.f, 0.f, 0.f, 0.f};

  int l16 = lane >> 4, c16 = lane & 15;  // K staging: 4 rows x 16 chunks / instr
  int l8 = lane >> 3,  c8 = lane & 7;    // V staging: 8 rows x 8 chunks / instr

  auto stage = [&](int buf, int kt) {
    int k0 = kt * 64;
#pragma unroll
    for (int i = 0; i < 4; i++) {
      int rl = w * 16 + i * 4 + l16;           // local key row
      int cg = c16 ^ (rl & 7);                 // global 16B chunk (swizzle)
      async_copy16(&Kl[buf][(w * 16 + i * 4) * 128],
                   kb + (size_t)(k0 + rl) * 128 + cg * 8);
    }
#pragma unroll
    for (int i = 0; i < 4; i++) {
      int ch = w * 32 + i * 8 + l8;            // channel row
      int cg = c8 ^ (ch & 7);
      async_copy16(&Vl[buf][(w * 32 + i * 8) * 64],
                   vt + (size_t)ch * NP + k0 + cg * 8);
    }
  };

  int KT = NP >> 6;
  stage(0, 0);
  __syncthreads();

  for (int kt = 0; kt < KT; kt++) {
    int buf = kt & 1;
    if (kt + 1 < KT) stage(buf ^ 1, kt + 1);
    int k0 = kt << 6;
    const u16* Kb = &Kl[buf][0];
    const u16* Vb = &Vl[buf][0];

    // S = Q @ K^T : 4 groups of 16 keys
    f32x4 S[4];
#pragma unroll
    for (int g = 0; g < 4; g++) {
      f32x4 s; s[0] = 0.f; s[1] = 0.f; s[2] = 0.f; s[3] = 0.f;
      int key = g * 16 + col;
      const u16* kr = Kb + key * 128;
#pragma unroll
      for (int r = 0; r < 4; r++) {
        s = MFMA16(aQ[r], *(const bf16x8*)(kr + ((((r << 2) + quad) ^ h8) << 3)), s);
      }
      if (k0 + key >= N) { s[0] = -1e30f; s[1] = -1e30f; s[2] = -1e30f; s[3] = -1e30f; }
      S[g] = s;
    }
    // online softmax (row = quad*4+r, stats across 16 col lanes)
    float tm[4], ts[4], al[4];
#pragma unroll
    for (int r = 0; r < 4; r++)
      tm[r] = fmaxf(fmaxf(S[0][r], S[1][r]), fmaxf(S[2][r], S[3][r]));
#pragma unroll
    for (int d = 1; d < 16; d <<= 1) {
#pragma unroll
      for (int r = 0; r < 4; r++) tm[r] = fmaxf(tm[r], __shfl_xor(tm[r], d, 64));
    }
    f32x4 P[4];
#pragma unroll
    for (int r = 0; r < 4; r++) {
      float mn = fmaxf(mr[r], tm[r]);
      al[r] = __expf(mr[r] - mn);
      mr[r] = mn;
      float acc = 0.f;
#pragma unroll
      for (int g = 0; g < 4; g++) { P[g][r] = __expf(S[g][r] - mn); acc += P[g][r]; }
      ts[r] = acc;
    }
#pragma unroll
    for (int d = 1; d < 16; d <<= 1) {
#pragma unroll
      for (int r = 0; r < 4; r++) ts[r] += __shfl_xor(ts[r], d, 64);
    }
#pragma unroll
    for (int r = 0; r < 4; r++) lr[r] = lr[r] * al[r] + ts[r];
#pragma unroll
    for (int nb = 0; nb < 8; nb++) {
      O[nb][0] *= al[0]; O[nb][1] *= al[1]; O[nb][2] *= al[2]; O[nb][3] *= al[3];
    }
    // P: C-layout -> A-layout via wave-private LDS
#pragma unroll
    for (int g = 0; g < 4; g++) {
#pragma unroll
      for (int r = 0; r < 4; r++)
        Pl[w][quad * 4 + r][g * 16 + col] = f2b(P[g][r]);
    }
    asm volatile("s_waitcnt lgkmcnt(0)" ::: "memory");
    bf16x8 aP0 = *(const bf16x8*)&Pl[w][col][quad * 8];
    bf16x8 aP1 = *(const bf16x8*)&Pl[w][col][32 + quad * 8];
    // O += P @ V
#pragma unroll
    for (int nb = 0; nb < 8; nb++) {
      int ch = nb * 16 + col;
      const u16* vr = Vb + ch * 64;
      O[nb] = MFMA16(aP0, *(const bf16x8*)(vr + (((quad) ^ h8) << 3)), O[nb]);
      O[nb] = MFMA16(aP1, *(const bf16x8*)(vr + (((4 + quad) ^ h8) << 3)), O[nb]);
    }
    __syncthreads();  // drain prefetch DMA + protect buf reuse
  }

  float il[4];
#pragma unroll
  for (int r = 0; r < 4; r++) il[r] = 1.0f / lr[r];
#pragma unroll
  for (int nb = 0; nb < 8; nb++) {
    int ch = nb * 16 + col;
#pragma unroll
    for (int r = 0; r < 4; r++) {
      int row = qbase + quad * 4 + r;
      if (row < N) {
        size_t idx = (size_t)row * 128 + ch;
        float val = O[nb][r] * il[r] + out2[idx] + ident[idx];
        out[idx] = val / (1.f + __expf(-val));  // silu
      }
    }
  }
}

extern "C" void kernel_launch(void* const* d_in, const int* in_sizes, int n_in,
                              void* d_out, int out_size, void* d_ws, size_t ws_size,
                              hipStream_t stream) {
  const float* x   = (const float*)d_in[0];
  const int*   ei  = (const int*)d_in[1];
  const float* W1  = (const float*)d_in[2];
  const float* b1  = (const float*)d_in[3];
  const float* W2  = (const float*)d_in[4];
  const float* b2  = (const float*)d_in[5];
  const float* g1  = (const float*)d_in[6];
  const float* be1 = (const float*)d_in[7];
  const float* g2  = (const float*)d_in[8];
  const float* be2 = (const float*)d_in[9];
  const float* Wq  = (const float*)d_in[10];
  const float* bq  = (const float*)d_in[11];
  const float* Wk  = (const float*)d_in[12];
  const float* bk  = (const float*)d_in[13];
  const float* Wv  = (const float*)d_in[14];
  const float* bv  = (const float*)d_in[15];
  const float* Wsw = (const float*)d_in[16];
  const float* bs  = (const float*)d_in[17];

  const int CIN = 256, C = 128;
  int N = in_sizes[0] / CIN;
  int E = in_sizes[1] / 2;
  int NP = (N + 63) & ~63;
  const int* src = ei;
  const int* dstp = ei + E;

  char* w = (char*)d_ws;
  size_t off = 0;
  auto alloc = [&](size_t bytes) -> void* {
    void* p = w + off;
    off = (off + bytes + 255) & ~(size_t)255;
    return p;
  };
  float* disb   = (float*)alloc((size_t)N * 4);
  int*   degi   = (int*)alloc((size_t)N * 4);
  int*   startb = (int*)alloc((size_t)N * 4);
  int*   cursor = (int*)alloc((size_t)N * 4);
  int*   counter= (int*)alloc(256);
  int*   adj    = (int*)alloc((size_t)E * 4);
  float* h      = (float*)alloc((size_t)N * C * 4);
  float* ident  = (float*)alloc((size_t)N * C * 4);
  float* cur    = (float*)alloc((size_t)N * C * 4);
  u16*   qbb    = (u16*)alloc((size_t)N * C * 2);
  u16*   kbb    = (u16*)alloc((size_t)NP * C * 2);
  u16*   vt     = (u16*)alloc((size_t)C * NP * 2);

  hipMemsetAsync(degi, 0, (size_t)N * 4, stream);
  hipMemsetAsync(cursor, 0, (size_t)N * 4, stream);
  hipMemsetAsync(counter, 0, 256, stream);
  hipMemsetAsync(kbb, 0, (size_t)NP * C * 2, stream);
  hipMemsetAsync(vt, 0, (size_t)C * NP * 2, stream);

  int gE = (E + 255) / 256, gN = (N + 255) / 256;
  degi_kernel<<<gE, 256, 0, stream>>>(dstp, degi, E);
  dis_kernel<<<gN, 256, 0, stream>>>(degi, disb, N);
  start_kernel<<<gN, 256, 0, stream>>>(degi, startb, counter, N);
  fill_kernel<<<gE, 256, 0, stream>>>(src, dstp, startb, cursor, adj, E);

  dim3 gg((N + 63) / 64, C / 64);
  // h1 = x @ W1 (bias folded into gather_ln)
  sgemm<<<gg, 256, 0, stream>>>(x, W1, nullptr, h, N, CIN, C, 0, 1.f, 0);
  // identity = x @ Ws + bs
  sgemm<<<gg, 256, 0, stream>>>(x, Wsw, bs, ident, N, CIN, C, GF_BIAS, 1.f, 0);
  // out1 = silu(LN1(gather(h1) + b1))
  gather_ln<<<(N + 3) / 4, 256, 0, stream>>>(h, disb, adj, startb, degi, b1, g1, be1, cur, N, 1);
  // h2 = out1 @ W2
  sgemm<<<gg, 256, 0, stream>>>(cur, W2, nullptr, h, N, C, C, 0, 1.f, 0);
  // out2 = LN2(gather(h2) + b2)
  gather_ln<<<(N + 3) / 4, 256, 0, stream>>>(h, disb, adj, startb, degi, b2, g2, be2, cur, N, 0);

  const float qscale = 0.08838834764831845f;  // 1/sqrt(128)
  sgemm<<<gg, 256, 0, stream>>>(cur, Wq, bq, qbb, N, C, C, GF_BIAS | GF_BF16, qscale, 0);
  sgemm<<<gg, 256, 0, stream>>>(cur, Wk, bk, kbb, N, C, C, GF_BIAS | GF_BF16, 1.f, 0);
  sgemm<<<gg, 256, 0, stream>>>(cur, Wv, bv, vt, N, C, C, GF_BIAS | GF_BF16 | GF_TRANS, 1.f, NP);

  flash_lds<<<(N + 63) / 64, 256, 0, stream>>>(qbb, kbb, vt, cur, ident, (float*)d_out, N, NP);
}

// Round 4
// 439.852 us; speedup vs baseline: 4.5465x; 1.4022x over previous
//
#include <hip/hip_runtime.h>
#include <hip/hip_bf16.h>

typedef unsigned short u16;
typedef unsigned int u32;
typedef __bf16 bf16x8 __attribute__((ext_vector_type(8)));
typedef float f32x4 __attribute__((ext_vector_type(4)));

#define GF_BIAS 1
#define GF_BF16 2
#define GF_TRANS 4

#define MFMA16(a, b, c) __builtin_amdgcn_mfma_f32_16x16x32_bf16(a, b, c, 0, 0, 0)

static __device__ __forceinline__ u16 f2b(float f) {
  u32 u = __float_as_uint(f);
  return (u16)((u + 0x7FFFu + ((u >> 16) & 1u)) >> 16);
}

// async 16B/lane global->LDS DMA; dst = uniform base + lane*16
static __device__ __forceinline__ void async_copy16(void* lds, const void* gp) {
  __builtin_amdgcn_global_load_lds(
      (const __attribute__((address_space(1))) unsigned int*)gp,
      (__attribute__((address_space(3))) unsigned int*)lds, 16, 0, 0);
}

// ---------------- CSR build ----------------
__global__ void degi_kernel(const int* __restrict__ dst, int* __restrict__ degi, int E) {
  int e = blockIdx.x * 256 + threadIdx.x;
  if (e < E) atomicAdd(&degi[dst[e]], 1);
}

__global__ void dis_kernel(const int* __restrict__ degi, float* __restrict__ d, int N) {
  int i = blockIdx.x * 256 + threadIdx.x;
  if (i < N) d[i] = rsqrtf((float)degi[i] + 1.0f);  // +1 = self loop
}

__global__ void start_kernel(const int* __restrict__ degi, int* __restrict__ startb,
                             int* __restrict__ counter, int N) {
  int i = blockIdx.x * 256 + threadIdx.x;
  if (i < N) startb[i] = atomicAdd(counter, degi[i]);
}

__global__ void fill_kernel(const int* __restrict__ src, const int* __restrict__ dst,
                            const int* __restrict__ startb, int* __restrict__ cursor,
                            int* __restrict__ adj, int E) {
  int e = blockIdx.x * 256 + threadIdx.x;
  if (e < E) {
    int d = dst[e];
    int p = atomicAdd(&cursor[d], 1);
    adj[startb[d] + p] = src[e];
  }
}

// ---------------- fp32 SGEMM: C[M,Nn] = A[M,K] @ B[K,Nn] ----------------
__global__ __launch_bounds__(256) void sgemm(
    const float* __restrict__ A, const float* __restrict__ B,
    const float* __restrict__ bias, void* __restrict__ Cout,
    int M, int K, int Nn, int flags, float oscale, int ldt)
{
  __shared__ float As[32][68];
  __shared__ float Bs[32][64];
  int tid = threadIdx.x;
  int bm = blockIdx.x * 64, bn = blockIdx.y * 64;
  int tx = tid & 15, ty = tid >> 4;
  float acc[4][4] = {{0.f}};
  int ar = tid >> 3, ac = (tid & 7) * 4;
  int br = tid >> 4, bc = (tid & 15) * 4;
  for (int k0 = 0; k0 < K; k0 += 32) {
#pragma unroll
    for (int i = 0; i < 2; i++) {
      int r = ar + i * 32;
      float4 a = make_float4(0.f, 0.f, 0.f, 0.f);
      if (bm + r < M) a = *(const float4*)&A[(size_t)(bm + r) * K + k0 + ac];
      As[ac + 0][r] = a.x; As[ac + 1][r] = a.y;
      As[ac + 2][r] = a.z; As[ac + 3][r] = a.w;
    }
#pragma unroll
    for (int i = 0; i < 2; i++) {
      int r = br + i * 16;
      *(float4*)&Bs[r][bc] = *(const float4*)&B[(size_t)(k0 + r) * Nn + bn + bc];
    }
    __syncthreads();
#pragma unroll
    for (int kk = 0; kk < 32; kk++) {
      float4 av = *(const float4*)&As[kk][ty * 4];
      float4 bv = *(const float4*)&Bs[kk][tx * 4];
      acc[0][0] += av.x * bv.x; acc[0][1] += av.x * bv.y; acc[0][2] += av.x * bv.z; acc[0][3] += av.x * bv.w;
      acc[1][0] += av.y * bv.x; acc[1][1] += av.y * bv.y; acc[1][2] += av.y * bv.z; acc[1][3] += av.y * bv.w;
      acc[2][0] += av.z * bv.x; acc[2][1] += av.z * bv.y; acc[2][2] += av.z * bv.z; acc[2][3] += av.z * bv.w;
      acc[3][0] += av.w * bv.x; acc[3][1] += av.w * bv.y; acc[3][2] += av.w * bv.z; acc[3][3] += av.w * bv.w;
    }
    __syncthreads();
  }
#pragma unroll
  for (int i = 0; i < 4; i++) {
    int row = bm + ty * 4 + i;
    if (row >= M) continue;
#pragma unroll
    for (int j = 0; j < 4; j++) {
      int c = bn + tx * 4 + j;
      float v = acc[i][j];
      if (flags & GF_BIAS) v += bias[c];
      v *= oscale;
      if (flags & GF_BF16) {
        u16 hb = f2b(v);
        if (flags & GF_TRANS) ((u16*)Cout)[(size_t)c * ldt + row] = hb;
        else                  ((u16*)Cout)[(size_t)row * Nn + c] = hb;
      } else {
        ((float*)Cout)[(size_t)row * Nn + c] = v;
      }
    }
  }
}

// ---------------- fused CSR gather + self-loop + bias + LN (+SiLU), wave per row ----------------
__global__ __launch_bounds__(256) void gather_ln(
    const float* __restrict__ h, const float* __restrict__ dis,
    const int* __restrict__ adj, const int* __restrict__ startb, const int* __restrict__ degi,
    const float* __restrict__ bias, const float* __restrict__ g, const float* __restrict__ beta,
    float* __restrict__ out, int N, int do_silu)
{
  int row = blockIdx.x * 4 + (threadIdx.x >> 6);
  int lane = threadIdx.x & 63;
  if (row >= N) return;
  int st = startb[row], dg = degi[row];
  float v0 = 0.f, v1 = 0.f;
  for (int base = 0; base < dg; base += 64) {
    int nb = min(64, dg - base);
    int myadj = 0; float mydis = 0.f;
    if (lane < nb) { myadj = adj[st + base + lane]; mydis = dis[myadj]; }
    int jj = 0;
    for (; jj + 4 <= nb; jj += 4) {
      int s0 = __shfl(myadj, jj), s1 = __shfl(myadj, jj + 1);
      int s2 = __shfl(myadj, jj + 2), s3 = __shfl(myadj, jj + 3);
      float w0 = __shfl(mydis, jj), w1 = __shfl(mydis, jj + 1);
      float w2 = __shfl(mydis, jj + 2), w3 = __shfl(mydis, jj + 3);
      const float* p0 = &h[(size_t)s0 * 128 + lane];
      const float* p1 = &h[(size_t)s1 * 128 + lane];
      const float* p2 = &h[(size_t)s2 * 128 + lane];
      const float* p3 = &h[(size_t)s3 * 128 + lane];
      v0 += w0 * p0[0]; v1 += w0 * p0[64];
      v0 += w1 * p1[0]; v1 += w1 * p1[64];
      v0 += w2 * p2[0]; v1 += w2 * p2[64];
      v0 += w3 * p3[0]; v1 += w3 * p3[64];
    }
    for (; jj < nb; jj++) {
      int s = __shfl(myadj, jj);
      float wv = __shfl(mydis, jj);
      const float* p = &h[(size_t)s * 128 + lane];
      v0 += wv * p[0]; v1 += wv * p[64];
    }
  }
  float dd = dis[row];
  const float* hp = &h[(size_t)row * 128 + lane];
  v0 = (v0 + dd * hp[0])  * dd + bias[lane];
  v1 = (v1 + dd * hp[64]) * dd + bias[64 + lane];
  float s = v0 + v1;
#pragma unroll
  for (int d = 32; d > 0; d >>= 1) s += __shfl_xor(s, d, 64);
  float mu = s * (1.0f / 128.0f);
  float d0 = v0 - mu, d1 = v1 - mu;
  float q = d0 * d0 + d1 * d1;
#pragma unroll
  for (int d = 32; d > 0; d >>= 1) q += __shfl_xor(q, d, 64);
  float rstd = rsqrtf(q * (1.0f / 128.0f) + 1e-5f);
  float o0 = d0 * rstd * g[lane]      + beta[lane];
  float o1 = d1 * rstd * g[64 + lane] + beta[64 + lane];
  if (do_silu) {
    o0 = o0 / (1.f + __expf(-o0));
    o1 = o1 / (1.f + __expf(-o1));
  }
  size_t base = (size_t)row * 128;
  out[base + lane] = o0;
  out[base + 64 + lane] = o1;
}

// ---------------- flash attention partial: Q-tile 64 x K-chunk, LDS-staged ----------------
// grid = (numQtiles, S). Each block: 16 rows/wave x 4 waves, keys [ks*CHUNK, ks*CHUNK+CHUNK).
// Writes unnormalized O (bf16) + m,l per row to workspace; attn_combine merges.
__global__ __launch_bounds__(256) void flash_part(
    const u16* __restrict__ qb, const u16* __restrict__ kb, const u16* __restrict__ vt,
    u16* __restrict__ Opart, float* __restrict__ mpart, float* __restrict__ lpart,
    int N, int NP, int CHUNK)
{
  __shared__ __align__(16) u16 Kl[64 * 128];   // [key][128ch], swizzled 16B chunks
  __shared__ __align__(16) u16 Vl[128 * 64];   // [ch][64key], swizzled 16B chunks
  __shared__ __align__(16) u16 Pl[4][16][72];  // per-wave P relayout, +8 pad
  int tid = threadIdx.x;
  int w = tid >> 6, lane = tid & 63;
  int col = lane & 15, quad = lane >> 4;
  int h8 = col & 7;
  int ks = blockIdx.y;
  int kstart = ks * CHUNK;
  int qbase = blockIdx.x * 64 + w * 16;

  int qr = qbase + col; if (qr > N - 1) qr = N - 1;
  const u16* qp = qb + (size_t)qr * 128 + quad * 8;
  bf16x8 aQ[4];
  aQ[0] = *(const bf16x8*)(qp);
  aQ[1] = *(const bf16x8*)(qp + 32);
  aQ[2] = *(const bf16x8*)(qp + 64);
  aQ[3] = *(const bf16x8*)(qp + 96);

  f32x4 O[8];
#pragma unroll
  for (int i = 0; i < 8; i++) { O[i][0] = 0.f; O[i][1] = 0.f; O[i][2] = 0.f; O[i][3] = 0.f; }
  float mr[4] = {-1e30f, -1e30f, -1e30f, -1e30f};
  float lr[4] = {0.f, 0.f, 0.f, 0.f};

  int l16 = lane >> 4, c16 = lane & 15;  // K staging: 4 rows x 16 chunks / instr
  int l8 = lane >> 3,  c8 = lane & 7;    // V staging: 8 rows x 8 chunks / instr

  int KT = (min(CHUNK, NP - kstart)) >> 6;

  for (int kt = 0; kt < KT; kt++) {
    int k0 = kstart + (kt << 6);
    // stage K/V tile (single buffer)
#pragma unroll
    for (int i = 0; i < 4; i++) {
      int rl = w * 16 + i * 4 + l16;
      int cg = c16 ^ (rl & 7);
      async_copy16(&Kl[(w * 16 + i * 4) * 128], kb + (size_t)(k0 + rl) * 128 + cg * 8);
    }
#pragma unroll
    for (int i = 0; i < 4; i++) {
      int ch = w * 32 + i * 8 + l8;
      int cg = c8 ^ (ch & 7);
      async_copy16(&Vl[(w * 32 + i * 8) * 64], vt + (size_t)ch * NP + k0 + cg * 8);
    }
    __syncthreads();  // drains DMA (compiler emits vmcnt(0) before barrier)

    // S = Q @ K^T : 4 groups of 16 keys
    f32x4 S[4];
#pragma unroll
    for (int g = 0; g < 4; g++) {
      f32x4 s; s[0] = 0.f; s[1] = 0.f; s[2] = 0.f; s[3] = 0.f;
      int key = g * 16 + col;
      const u16* kr = Kl + key * 128;
#pragma unroll
      for (int r = 0; r < 4; r++) {
        s = MFMA16(aQ[r], *(const bf16x8*)(kr + ((((r << 2) + quad) ^ h8) << 3)), s);
      }
      if (k0 + key >= N) { s[0] = -1e30f; s[1] = -1e30f; s[2] = -1e30f; s[3] = -1e30f; }
      S[g] = s;
    }
    // online softmax (row = quad*4+r, stats across 16 col lanes)
    float tm[4], ts[4], al[4];
#pragma unroll
    for (int r = 0; r < 4; r++)
      tm[r] = fmaxf(fmaxf(S[0][r], S[1][r]), fmaxf(S[2][r], S[3][r]));
#pragma unroll
    for (int d = 1; d < 16; d <<= 1) {
#pragma unroll
      for (int r = 0; r < 4; r++) tm[r] = fmaxf(tm[r], __shfl_xor(tm[r], d, 64));
    }
    f32x4 P[4];
#pragma unroll
    for (int r = 0; r < 4; r++) {
      float mn = fmaxf(mr[r], tm[r]);
      al[r] = __expf(mr[r] - mn);
      mr[r] = mn;
      float acc = 0.f;
#pragma unroll
      for (int g = 0; g < 4; g++) { P[g][r] = __expf(S[g][r] - mn); acc += P[g][r]; }
      ts[r] = acc;
    }
#pragma unroll
    for (int d = 1; d < 16; d <<= 1) {
#pragma unroll
      for (int r = 0; r < 4; r++) ts[r] += __shfl_xor(ts[r], d, 64);
    }
#pragma unroll
    for (int r = 0; r < 4; r++) lr[r] = lr[r] * al[r] + ts[r];
#pragma unroll
    for (int nb = 0; nb < 8; nb++) {
      O[nb][0] *= al[0]; O[nb][1] *= al[1]; O[nb][2] *= al[2]; O[nb][3] *= al[3];
    }
    // P: C-layout -> A-layout via wave-private LDS
#pragma unroll
    for (int g = 0; g < 4; g++) {
#pragma unroll
      for (int r = 0; r < 4; r++)
        Pl[w][quad * 4 + r][g * 16 + col] = f2b(P[g][r]);
    }
    asm volatile("s_waitcnt lgkmcnt(0)" ::: "memory");
    bf16x8 aP0 = *(const bf16x8*)&Pl[w][col][quad * 8];
    bf16x8 aP1 = *(const bf16x8*)&Pl[w][col][32 + quad * 8];
    // O += P @ V
#pragma unroll
    for (int nb = 0; nb < 8; nb++) {
      int ch = nb * 16 + col;
      const u16* vr = Vl + ch * 64;
      O[nb] = MFMA16(aP0, *(const bf16x8*)(vr + (((quad) ^ h8) << 3)), O[nb]);
      O[nb] = MFMA16(aP1, *(const bf16x8*)(vr + (((4 + quad) ^ h8) << 3)), O[nb]);
    }
    __syncthreads();  // protect Kl/Vl before next stage
  }

  // write partials (unnormalized O as bf16; m,l as f32)
#pragma unroll
  for (int nb = 0; nb < 8; nb++) {
    int ch = nb * 16 + col;
#pragma unroll
    for (int r = 0; r < 4; r++) {
      int row = qbase + quad * 4 + r;
      if (row < N)
        Opart[((size_t)ks * NP + row) * 128 + ch] = f2b(O[nb][r]);
    }
  }
  if (col == 0) {
#pragma unroll
    for (int r = 0; r < 4; r++) {
      int row = qbase + quad * 4 + r;
      if (row < N) {
        mpart[(size_t)ks * NP + row] = mr[r];
        lpart[(size_t)ks * NP + row] = lr[r];
      }
    }
  }
}

// ---------------- combine K-split partials + out2 + identity + SiLU ----------------
__global__ __launch_bounds__(256) void attn_combine(
    const u16* __restrict__ Opart, const float* __restrict__ mpart, const float* __restrict__ lpart,
    const float* __restrict__ out2, const float* __restrict__ ident, float* __restrict__ out,
    int N, int NP, int S)
{
  int row = blockIdx.x * 2 + (threadIdx.x >> 7);
  int ch = threadIdx.x & 127;
  if (row >= N) return;
  float mmax = -1e30f;
  for (int u = 0; u < S; u++) mmax = fmaxf(mmax, mpart[(size_t)u * NP + row]);
  float num = 0.f, den = 0.f;
  for (int u = 0; u < S; u++) {
    float wv = __expf(mpart[(size_t)u * NP + row] - mmax);
    u32 b = Opart[((size_t)u * NP + row) * 128 + ch];
    num += wv * __uint_as_float(b << 16);
    den += wv * lpart[(size_t)u * NP + row];
  }
  size_t idx = (size_t)row * 128 + ch;
  float val = num / den + out2[idx] + ident[idx];
  out[idx] = val / (1.f + __expf(-val));  // silu
}

extern "C" void kernel_launch(void* const* d_in, const int* in_sizes, int n_in,
                              void* d_out, int out_size, void* d_ws, size_t ws_size,
                              hipStream_t stream) {
  const float* x   = (const float*)d_in[0];
  const int*   ei  = (const int*)d_in[1];
  const float* W1  = (const float*)d_in[2];
  const float* b1  = (const float*)d_in[3];
  const float* W2  = (const float*)d_in[4];
  const float* b2  = (const float*)d_in[5];
  const float* g1  = (const float*)d_in[6];
  const float* be1 = (const float*)d_in[7];
  const float* g2  = (const float*)d_in[8];
  const float* be2 = (const float*)d_in[9];
  const float* Wq  = (const float*)d_in[10];
  const float* bq  = (const float*)d_in[11];
  const float* Wk  = (const float*)d_in[12];
  const float* bk  = (const float*)d_in[13];
  const float* Wv  = (const float*)d_in[14];
  const float* bv  = (const float*)d_in[15];
  const float* Wsw = (const float*)d_in[16];
  const float* bs  = (const float*)d_in[17];

  const int CIN = 256, C = 128;
  int N = in_sizes[0] / CIN;
  int E = in_sizes[1] / 2;
  int NP = (N + 63) & ~63;
  const int* src = ei;
  const int* dstp = ei + E;

  const int S = 8;
  int numQT = NP / 64;
  int CHUNK = ((numQT + S - 1) / S) * 64;  // keys per split, mult of 64

  char* w = (char*)d_ws;
  size_t off = 0;
  auto alloc = [&](size_t bytes) -> void* {
    void* p = w + off;
    off = (off + bytes + 255) & ~(size_t)255;
    return p;
  };
  float* disb   = (float*)alloc((size_t)N * 4);
  int*   degi   = (int*)alloc((size_t)N * 4);
  int*   startb = (int*)alloc((size_t)N * 4);
  int*   cursor = (int*)alloc((size_t)N * 4);
  int*   counter= (int*)alloc(256);
  int*   adj    = (int*)alloc((size_t)E * 4);
  float* h      = (float*)alloc((size_t)N * C * 4);
  float* ident  = (float*)alloc((size_t)N * C * 4);
  float* cur    = (float*)alloc((size_t)N * C * 4);
  u16*   qbb    = (u16*)alloc((size_t)N * C * 2);
  u16*   kbb    = (u16*)alloc((size_t)NP * C * 2);
  u16*   vt     = (u16*)alloc((size_t)C * NP * 2);
  u16*   Opart  = (u16*)alloc((size_t)S * NP * C * 2);
  float* mpart  = (float*)alloc((size_t)S * NP * 4);
  float* lpart  = (float*)alloc((size_t)S * NP * 4);

  hipMemsetAsync(degi, 0, (size_t)N * 4, stream);
  hipMemsetAsync(cursor, 0, (size_t)N * 4, stream);
  hipMemsetAsync(counter, 0, 256, stream);
  hipMemsetAsync(kbb, 0, (size_t)NP * C * 2, stream);
  hipMemsetAsync(vt, 0, (size_t)C * NP * 2, stream);

  int gE = (E + 255) / 256, gN = (N + 255) / 256;
  degi_kernel<<<gE, 256, 0, stream>>>(dstp, degi, E);
  dis_kernel<<<gN, 256, 0, stream>>>(degi, disb, N);
  start_kernel<<<gN, 256, 0, stream>>>(degi, startb, counter, N);
  fill_kernel<<<gE, 256, 0, stream>>>(src, dstp, startb, cursor, adj, E);

  dim3 gg((N + 63) / 64, C / 64);
  // h1 = x @ W1 (bias folded into gather_ln)
  sgemm<<<gg, 256, 0, stream>>>(x, W1, nullptr, h, N, CIN, C, 0, 1.f, 0);
  // identity = x @ Ws + bs
  sgemm<<<gg, 256, 0, stream>>>(x, Wsw, bs, ident, N, CIN, C, GF_BIAS, 1.f, 0);
  // out1 = silu(LN1(gather(h1) + b1))
  gather_ln<<<(N + 3) / 4, 256, 0, stream>>>(h, disb, adj, startb, degi, b1, g1, be1, cur, N, 1);
  // h2 = out1 @ W2
  sgemm<<<gg, 256, 0, stream>>>(cur, W2, nullptr, h, N, C, C, 0, 1.f, 0);
  // out2 = LN2(gather(h2) + b2)
  gather_ln<<<(N + 3) / 4, 256, 0, stream>>>(h, disb, adj, startb, degi, b2, g2, be2, cur, N, 0);

  const float qscale = 0.08838834764831845f;  // 1/sqrt(128)
  sgemm<<<gg, 256, 0, stream>>>(cur, Wq, bq, qbb, N, C, C, GF_BIAS | GF_BF16, qscale, 0);
  sgemm<<<gg, 256, 0, stream>>>(cur, Wk, bk, kbb, N, C, C, GF_BIAS | GF_BF16, 1.f, 0);
  sgemm<<<gg, 256, 0, stream>>>(cur, Wv, bv, vt, N, C, C, GF_BIAS | GF_BF16 | GF_TRANS, 1.f, NP);

  dim3 fg(numQT, S);
  flash_part<<<fg, 256, 0, stream>>>(qbb, kbb, vt, Opart, mpart, lpart, N, NP, CHUNK);
  attn_combine<<<(N + 1) / 2, 256, 0, stream>>>(Opart, mpart, lpart, cur, ident,
                                                (float*)d_out, N, NP, S);
}

// Round 5
// 389.313 us; speedup vs baseline: 5.1367x; 1.1298x over previous
//
#include <hip/hip_runtime.h>
#include <hip/hip_bf16.h>

typedef unsigned short u16;
typedef unsigned int u32;
typedef __bf16 bf16x8 __attribute__((ext_vector_type(8)));
typedef float f32x4 __attribute__((ext_vector_type(4)));

#define GF_BIAS 1
#define GF_BF16 2
#define GF_TRANS 4

#define MFMA16(a, b, c) __builtin_amdgcn_mfma_f32_16x16x32_bf16(a, b, c, 0, 0, 0)

static __device__ __forceinline__ u16 f2b(float f) {
  u32 u = __float_as_uint(f);
  return (u16)((u + 0x7FFFu + ((u >> 16) & 1u)) >> 16);
}

// async 16B/lane global->LDS DMA; dst = uniform base + lane*16
static __device__ __forceinline__ void async_copy16(void* lds, const void* gp) {
  __builtin_amdgcn_global_load_lds(
      (const __attribute__((address_space(1))) unsigned int*)gp,
      (__attribute__((address_space(3))) unsigned int*)lds, 16, 0, 0);
}

// ---------------- CSR build ----------------
__global__ void degi_kernel(const int* __restrict__ dst, int* __restrict__ degi, int E) {
  int e = blockIdx.x * 256 + threadIdx.x;
  if (e < E) atomicAdd(&degi[dst[e]], 1);
}

__global__ void dis_kernel(const int* __restrict__ degi, float* __restrict__ d, int N) {
  int i = blockIdx.x * 256 + threadIdx.x;
  if (i < N) d[i] = rsqrtf((float)degi[i] + 1.0f);  // +1 = self loop
}

__global__ void start_kernel(const int* __restrict__ degi, int* __restrict__ startb,
                             int* __restrict__ counter, int N) {
  int i = blockIdx.x * 256 + threadIdx.x;
  if (i < N) startb[i] = atomicAdd(counter, degi[i]);
}

__global__ void fill_kernel(const int* __restrict__ src, const int* __restrict__ dst,
                            const int* __restrict__ startb, int* __restrict__ cursor,
                            int* __restrict__ adj, int E) {
  int e = blockIdx.x * 256 + threadIdx.x;
  if (e < E) {
    int d = dst[e];
    int p = atomicAdd(&cursor[d], 1);
    adj[startb[d] + p] = src[e];
  }
}

// ---------------- casts ----------------
__global__ void cast_x_kernel(const float* __restrict__ x, u16* __restrict__ xb, int n4) {
  int t = blockIdx.x * 256 + threadIdx.x;
  if (t >= n4) return;
  float4 v = *(const float4*)&x[t * 4];
  ushort4 o;
  o.x = f2b(v.x); o.y = f2b(v.y); o.z = f2b(v.z); o.w = f2b(v.w);
  *(ushort4*)&xb[t * 4] = o;
}

// transpose+cast 6 weights: W[K,128] f32 -> Wt[128,K] bf16, packed contiguous
__global__ void cast_w_kernel(const float* __restrict__ W1, const float* __restrict__ Ws,
                              const float* __restrict__ W2, const float* __restrict__ Wq,
                              const float* __restrict__ Wk, const float* __restrict__ Wv,
                              u16* __restrict__ out) {
  int t = blockIdx.x * 256 + threadIdx.x;
  if (t >= 131072) return;
  const float* src; int K, base, loc;
  if (t < 65536) {
    if (t < 32768) { src = W1; base = 0; } else { src = Ws; base = 32768; }
    loc = t - base; K = 256;
  } else {
    int seg = (t - 65536) >> 14;
    src = (seg == 0) ? W2 : (seg == 1) ? Wq : (seg == 2) ? Wk : Wv;
    base = 65536 + seg * 16384; loc = t & 16383; K = 128;
  }
  int k = loc >> 7, c = loc & 127;          // src is [K,128]: loc = k*128 + c
  out[base + c * K + k] = f2b(src[loc]);    // out is [128,K]
}

// ---------------- bf16 MFMA GEMM: C[M,128] = A[M,K] @ Wt[128,K]^T ----------------
// 1 wave / block, 16 rows, all 128 cols in registers; B-frags straight from L2.
__global__ __launch_bounds__(64) void bgemm(
    const u16* __restrict__ A, const u16* __restrict__ Wt,
    const float* __restrict__ bias, void* __restrict__ Cout,
    int M, int K, int flags, float oscale, int ldt)
{
  int lane = threadIdx.x;
  int col = lane & 15, quad = lane >> 4;
  int row0 = blockIdx.x * 16;
  int ar = row0 + col; if (ar > M - 1) ar = M - 1;
  const u16* ap = A + (size_t)ar * K + quad * 8;
  f32x4 O[8];
#pragma unroll
  for (int i = 0; i < 8; i++) { O[i][0] = 0.f; O[i][1] = 0.f; O[i][2] = 0.f; O[i][3] = 0.f; }
  for (int k0 = 0; k0 < K; k0 += 32) {
    bf16x8 aA = *(const bf16x8*)(ap + k0);
#pragma unroll
    for (int nb = 0; nb < 8; nb++) {
      const u16* bp = Wt + (size_t)(nb * 16 + col) * K + k0 + quad * 8;
      O[nb] = MFMA16(aA, *(const bf16x8*)bp, O[nb]);
    }
  }
#pragma unroll
  for (int nb = 0; nb < 8; nb++) {
    int ch = nb * 16 + col;
    float bv = (flags & GF_BIAS) ? bias[ch] : 0.f;
#pragma unroll
    for (int r = 0; r < 4; r++) {
      int row = row0 + quad * 4 + r;
      if (row >= M) continue;
      float v = (O[nb][r] + bv) * oscale;
      if (flags & GF_BF16) {
        u16 hb = f2b(v);
        if (flags & GF_TRANS) ((u16*)Cout)[(size_t)ch * ldt + row] = hb;
        else                  ((u16*)Cout)[(size_t)row * 128 + ch] = hb;
      } else {
        ((float*)Cout)[(size_t)row * 128 + ch] = v;
      }
    }
  }
}

// ---------------- fused CSR gather + self-loop + bias + LN (+SiLU), wave per row ----------------
// Also emits bf16 copy for downstream MFMA GEMMs.
__global__ __launch_bounds__(256) void gather_ln(
    const float* __restrict__ h, const float* __restrict__ dis,
    const int* __restrict__ adj, const int* __restrict__ startb, const int* __restrict__ degi,
    const float* __restrict__ bias, const float* __restrict__ g, const float* __restrict__ beta,
    float* __restrict__ out, u16* __restrict__ outb, int N, int do_silu)
{
  int row = blockIdx.x * 4 + (threadIdx.x >> 6);
  int lane = threadIdx.x & 63;
  if (row >= N) return;
  int st = startb[row], dg = degi[row];
  float v0 = 0.f, v1 = 0.f;
  for (int base = 0; base < dg; base += 64) {
    int nb = min(64, dg - base);
    int myadj = 0; float mydis = 0.f;
    if (lane < nb) { myadj = adj[st + base + lane]; mydis = dis[myadj]; }
    int jj = 0;
    for (; jj + 4 <= nb; jj += 4) {
      int s0 = __shfl(myadj, jj), s1 = __shfl(myadj, jj + 1);
      int s2 = __shfl(myadj, jj + 2), s3 = __shfl(myadj, jj + 3);
      float w0 = __shfl(mydis, jj), w1 = __shfl(mydis, jj + 1);
      float w2 = __shfl(mydis, jj + 2), w3 = __shfl(mydis, jj + 3);
      const float* p0 = &h[(size_t)s0 * 128 + lane];
      const float* p1 = &h[(size_t)s1 * 128 + lane];
      const float* p2 = &h[(size_t)s2 * 128 + lane];
      const float* p3 = &h[(size_t)s3 * 128 + lane];
      v0 += w0 * p0[0]; v1 += w0 * p0[64];
      v0 += w1 * p1[0]; v1 += w1 * p1[64];
      v0 += w2 * p2[0]; v1 += w2 * p2[64];
      v0 += w3 * p3[0]; v1 += w3 * p3[64];
    }
    for (; jj < nb; jj++) {
      int s = __shfl(myadj, jj);
      float wv = __shfl(mydis, jj);
      const float* p = &h[(size_t)s * 128 + lane];
      v0 += wv * p[0]; v1 += wv * p[64];
    }
  }
  float dd = dis[row];
  const float* hp = &h[(size_t)row * 128 + lane];
  v0 = (v0 + dd * hp[0])  * dd + bias[lane];
  v1 = (v1 + dd * hp[64]) * dd + bias[64 + lane];
  float s = v0 + v1;
#pragma unroll
  for (int d = 32; d > 0; d >>= 1) s += __shfl_xor(s, d, 64);
  float mu = s * (1.0f / 128.0f);
  float d0 = v0 - mu, d1 = v1 - mu;
  float q = d0 * d0 + d1 * d1;
#pragma unroll
  for (int d = 32; d > 0; d >>= 1) q += __shfl_xor(q, d, 64);
  float rstd = rsqrtf(q * (1.0f / 128.0f) + 1e-5f);
  float o0 = d0 * rstd * g[lane]      + beta[lane];
  float o1 = d1 * rstd * g[64 + lane] + beta[64 + lane];
  if (do_silu) {
    o0 = o0 / (1.f + __expf(-o0));
    o1 = o1 / (1.f + __expf(-o1));
  }
  size_t base = (size_t)row * 128;
  out[base + lane] = o0;
  out[base + 64 + lane] = o1;
  outb[base + lane] = f2b(o0);
  outb[base + 64 + lane] = f2b(o1);
}

// ---------------- flash attention partial: 128-row Q tile (32/wave) x K-chunk ----------------
// Fixed softmax base (scores bounded, no max tracking): P = exp(S) directly, padded
// keys masked to -1e30 -> exp = 0 (so K/V pad rows need no zeroing).
// Writes unnormalized O (bf16) + per-row l to workspace; attn_combine merges.
__global__ __launch_bounds__(256, 3) void flash_part(
    const u16* __restrict__ qb, const u16* __restrict__ kb, const u16* __restrict__ vt,
    u16* __restrict__ Opart, float* __restrict__ lpart,
    int N, int NP, int CHUNK)
{
  __shared__ __align__(16) u16 Kl[64 * 128];   // [key][128ch], swizzled 16B chunks
  __shared__ __align__(16) u16 Vl[128 * 64];   // [ch][64key], swizzled 16B chunks
  __shared__ __align__(16) u16 Pl[4][32][72];  // per-wave P relayout, +8 pad
  int tid = threadIdx.x;
  int w = tid >> 6, lane = tid & 63;
  int col = lane & 15, quad = lane >> 4;
  int h8 = col & 7;
  int ks = blockIdx.y;
  int kstart = ks * CHUNK;
  int qbase = blockIdx.x * 128 + w * 32;

  bf16x8 aQ[2][4];
#pragma unroll
  for (int rg = 0; rg < 2; rg++) {
    int qr = qbase + rg * 16 + col; if (qr > N - 1) qr = N - 1;
    const u16* qp = qb + (size_t)qr * 128 + quad * 8;
    aQ[rg][0] = *(const bf16x8*)(qp);
    aQ[rg][1] = *(const bf16x8*)(qp + 32);
    aQ[rg][2] = *(const bf16x8*)(qp + 64);
    aQ[rg][3] = *(const bf16x8*)(qp + 96);
  }

  f32x4 O[2][8];
#pragma unroll
  for (int rg = 0; rg < 2; rg++)
#pragma unroll
    for (int i = 0; i < 8; i++) { O[rg][i][0] = 0.f; O[rg][i][1] = 0.f; O[rg][i][2] = 0.f; O[rg][i][3] = 0.f; }
  float lr[2][4] = {{0.f, 0.f, 0.f, 0.f}, {0.f, 0.f, 0.f, 0.f}};

  int l16 = lane >> 4, c16 = lane & 15;  // K staging: 4 rows x 16 chunks / instr
  int l8 = lane >> 3,  c8 = lane & 7;    // V staging: 8 rows x 8 chunks / instr

  int KT = (min(CHUNK, NP - kstart)) >> 6;

  for (int kt = 0; kt < KT; kt++) {
    int k0 = kstart + (kt << 6);
    // stage K/V tile
#pragma unroll
    for (int i = 0; i < 4; i++) {
      int rl = w * 16 + i * 4 + l16;
      int cg = c16 ^ (rl & 7);
      async_copy16(&Kl[(w * 16 + i * 4) * 128], kb + (size_t)(k0 + rl) * 128 + cg * 8);
    }
#pragma unroll
    for (int i = 0; i < 4; i++) {
      int ch = w * 32 + i * 8 + l8;
      int cg = c8 ^ (ch & 7);
      async_copy16(&Vl[(w * 32 + i * 8) * 64], vt + (size_t)ch * NP + k0 + cg * 8);
    }
    __syncthreads();  // drains DMA

    bool edge = (k0 + 64 > N);
#pragma unroll
    for (int g = 0; g < 4; g++) {
      const u16* kr = Kl + (g * 16 + col) * 128;
      bf16x8 kf0 = *(const bf16x8*)(kr + (((0 + quad) ^ h8) << 3));
      bf16x8 kf1 = *(const bf16x8*)(kr + (((4 + quad) ^ h8) << 3));
      bf16x8 kf2 = *(const bf16x8*)(kr + (((8 + quad) ^ h8) << 3));
      bf16x8 kf3 = *(const bf16x8*)(kr + (((12 + quad) ^ h8) << 3));
      f32x4 s0; s0[0] = 0.f; s0[1] = 0.f; s0[2] = 0.f; s0[3] = 0.f;
      f32x4 s1 = s0;
      s0 = MFMA16(aQ[0][0], kf0, s0); s1 = MFMA16(aQ[1][0], kf0, s1);
      s0 = MFMA16(aQ[0][1], kf1, s0); s1 = MFMA16(aQ[1][1], kf1, s1);
      s0 = MFMA16(aQ[0][2], kf2, s0); s1 = MFMA16(aQ[1][2], kf2, s1);
      s0 = MFMA16(aQ[0][3], kf3, s0); s1 = MFMA16(aQ[1][3], kf3, s1);
      if (edge && (k0 + g * 16 + col >= N)) {
        s0[0] = -1e30f; s0[1] = -1e30f; s0[2] = -1e30f; s0[3] = -1e30f;
        s1 = s0;
      }
      // P = exp(S); accumulate l per-lane; stash bf16 (RTZ) into LDS for relayout
#pragma unroll
      for (int r = 0; r < 4; r++) {
        float p0 = __expf(s0[r]);
        float p1 = __expf(s1[r]);
        lr[0][r] += p0;
        lr[1][r] += p1;
        Pl[w][quad * 4 + r][g * 16 + col]      = (u16)(__float_as_uint(p0) >> 16);
        Pl[w][16 + quad * 4 + r][g * 16 + col] = (u16)(__float_as_uint(p1) >> 16);
      }
    }
    asm volatile("s_waitcnt lgkmcnt(0)" ::: "memory");
    bf16x8 aP[2][2];
#pragma unroll
    for (int rg = 0; rg < 2; rg++) {
      aP[rg][0] = *(const bf16x8*)&Pl[w][rg * 16 + col][quad * 8];
      aP[rg][1] = *(const bf16x8*)&Pl[w][rg * 16 + col][32 + quad * 8];
    }
    // O += P @ V (V-frags register-reused across both row groups)
#pragma unroll
    for (int nb = 0; nb < 8; nb++) {
      const u16* vr = Vl + (nb * 16 + col) * 64;
      bf16x8 vf0 = *(const bf16x8*)(vr + (((0 + quad) ^ h8) << 3));
      bf16x8 vf1 = *(const bf16x8*)(vr + (((4 + quad) ^ h8) << 3));
      O[0][nb] = MFMA16(aP[0][0], vf0, O[0][nb]);
      O[0][nb] = MFMA16(aP[0][1], vf1, O[0][nb]);
      O[1][nb] = MFMA16(aP[1][0], vf0, O[1][nb]);
      O[1][nb] = MFMA16(aP[1][1], vf1, O[1][nb]);
    }
    __syncthreads();  // protect Kl/Vl before next stage
  }

  // row-sum l across the 16 col lanes (once, at the end)
#pragma unroll
  for (int d = 1; d < 16; d <<= 1) {
#pragma unroll
    for (int rg = 0; rg < 2; rg++)
#pragma unroll
      for (int r = 0; r < 4; r++) lr[rg][r] += __shfl_xor(lr[rg][r], d, 64);
  }

  // write partials
#pragma unroll
  for (int rg = 0; rg < 2; rg++) {
#pragma unroll
    for (int nb = 0; nb < 8; nb++) {
      int ch = nb * 16 + col;
#pragma unroll
      for (int r = 0; r < 4; r++) {
        int row = qbase + rg * 16 + quad * 4 + r;
        if (row < N)
          Opart[((size_t)ks * NP + row) * 128 + ch] = f2b(O[rg][nb][r]);
      }
    }
  }
  if (col == 0) {
#pragma unroll
    for (int rg = 0; rg < 2; rg++)
#pragma unroll
      for (int r = 0; r < 4; r++) {
        int row = qbase + rg * 16 + quad * 4 + r;
        if (row < N) lpart[(size_t)ks * NP + row] = lr[rg][r];
      }
  }
}

// ---------------- combine K-split partials + out2 + identity + SiLU ----------------
__global__ __launch_bounds__(256) void attn_combine(
    const u16* __restrict__ Opart, const float* __restrict__ lpart,
    const float* __restrict__ out2, const float* __restrict__ ident, float* __restrict__ out,
    int N, int NP, int S)
{
  int row = blockIdx.x * 2 + (threadIdx.x >> 7);
  int ch = threadIdx.x & 127;
  if (row >= N) return;
  float num = 0.f, den = 0.f;
  for (int u = 0; u < S; u++) {
    u32 b = Opart[((size_t)u * NP + row) * 128 + ch];
    num += __uint_as_float(b << 16);
    den += lpart[(size_t)u * NP + row];
  }
  size_t idx = (size_t)row * 128 + ch;
  float val = num / den + out2[idx] + ident[idx];
  out[idx] = val / (1.f + __expf(-val));  // silu
}

extern "C" void kernel_launch(void* const* d_in, const int* in_sizes, int n_in,
                              void* d_out, int out_size, void* d_ws, size_t ws_size,
                              hipStream_t stream) {
  const float* x   = (const float*)d_in[0];
  const int*   ei  = (const int*)d_in[1];
  const float* W1  = (const float*)d_in[2];
  const float* b1  = (const float*)d_in[3];
  const float* W2  = (const float*)d_in[4];
  const float* b2  = (const float*)d_in[5];
  const float* g1  = (const float*)d_in[6];
  const float* be1 = (const float*)d_in[7];
  const float* g2  = (const float*)d_in[8];
  const float* be2 = (const float*)d_in[9];
  const float* Wq  = (const float*)d_in[10];
  const float* bq  = (const float*)d_in[11];
  const float* Wk  = (const float*)d_in[12];
  const float* bk  = (const float*)d_in[13];
  const float* Wv  = (const float*)d_in[14];
  const float* bv  = (const float*)d_in[15];
  const float* Wsw = (const float*)d_in[16];
  const float* bs  = (const float*)d_in[17];

  const int CIN = 256, C = 128;
  int N = in_sizes[0] / CIN;
  int E = in_sizes[1] / 2;
  int NP = (N + 63) & ~63;
  const int* src = ei;
  const int* dstp = ei + E;

  const int S = 8;
  int tiles = NP / 64;
  int CHUNK = ((tiles + S - 1) / S) * 64;  // keys per split, mult of 64

  char* w = (char*)d_ws;
  size_t off = 0;
  auto alloc = [&](size_t bytes) -> void* {
    void* p = w + off;
    off = (off + bytes + 255) & ~(size_t)255;
    return p;
  };
  // degi/cursor/counter contiguous -> one memset
  int*   degi   = (int*)alloc((size_t)N * 4);
  int*   cursor = (int*)alloc((size_t)N * 4);
  int*   counter= (int*)alloc(256);
  size_t zlen   = off;
  float* disb   = (float*)alloc((size_t)N * 4);
  int*   startb = (int*)alloc((size_t)N * 4);
  int*   adj    = (int*)alloc((size_t)E * 4);
  float* h      = (float*)alloc((size_t)N * C * 4);
  float* ident  = (float*)alloc((size_t)N * C * 4);
  float* cur    = (float*)alloc((size_t)N * C * 4);
  u16*   xb     = (u16*)alloc((size_t)N * CIN * 2);
  u16*   curb   = (u16*)alloc((size_t)N * C * 2);
  u16*   wt     = (u16*)alloc((size_t)131072 * 2);
  u16*   qbb    = (u16*)alloc((size_t)N * C * 2);
  u16*   kbb    = (u16*)alloc((size_t)NP * C * 2);
  u16*   vt     = (u16*)alloc((size_t)C * NP * 2);
  u16*   Opart  = (u16*)alloc((size_t)S * NP * C * 2);
  float* lpart  = (float*)alloc((size_t)S * NP * 4);

  u16* wt1 = wt;            // [128,256]
  u16* wts = wt + 32768;    // [128,256]
  u16* wt2 = wt + 65536;    // [128,128]
  u16* wtq = wt + 81920;
  u16* wtk = wt + 98304;
  u16* wtv = wt + 114688;

  hipMemsetAsync(degi, 0, zlen, stream);

  int gE = (E + 255) / 256, gN = (N + 255) / 256;
  degi_kernel<<<gE, 256, 0, stream>>>(dstp, degi, E);
  dis_kernel<<<gN, 256, 0, stream>>>(degi, disb, N);
  start_kernel<<<gN, 256, 0, stream>>>(degi, startb, counter, N);
  fill_kernel<<<gE, 256, 0, stream>>>(src, dstp, startb, cursor, adj, E);

  int n4 = N * CIN / 4;
  cast_x_kernel<<<(n4 + 255) / 256, 256, 0, stream>>>(x, xb, n4);
  cast_w_kernel<<<512, 256, 0, stream>>>(W1, Wsw, W2, Wq, Wk, Wv, wt);

  int gbg = (N + 15) / 16;
  // h1 = x @ W1 (bias folded into gather_ln)
  bgemm<<<gbg, 64, 0, stream>>>(xb, wt1, nullptr, h, N, CIN, 0, 1.f, 0);
  // identity = x @ Ws + bs
  bgemm<<<gbg, 64, 0, stream>>>(xb, wts, bs, ident, N, CIN, GF_BIAS, 1.f, 0);
  // out1 = silu(LN1(gather(h1) + b1))
  gather_ln<<<(N + 3) / 4, 256, 0, stream>>>(h, disb, adj, startb, degi, b1, g1, be1, cur, curb, N, 1);
  // h2 = out1 @ W2
  bgemm<<<gbg, 64, 0, stream>>>(curb, wt2, nullptr, h, N, C, 0, 1.f, 0);
  // out2 = LN2(gather(h2) + b2)
  gather_ln<<<(N + 3) / 4, 256, 0, stream>>>(h, disb, adj, startb, degi, b2, g2, be2, cur, curb, N, 0);

  const float qscale = 0.08838834764831845f;  // 1/sqrt(128)
  bgemm<<<gbg, 64, 0, stream>>>(curb, wtq, bq, qbb, N, C, GF_BIAS | GF_BF16, qscale, 0);
  bgemm<<<gbg, 64, 0, stream>>>(curb, wtk, bk, kbb, N, C, GF_BIAS | GF_BF16, 1.f, 0);
  bgemm<<<gbg, 64, 0, stream>>>(curb, wtv, bv, vt, N, C, GF_BIAS | GF_BF16 | GF_TRANS, 1.f, NP);

  dim3 fg((N + 127) / 128, S);
  flash_part<<<fg, 256, 0, stream>>>(qbb, kbb, vt, Opart, lpart, N, NP, CHUNK);
  attn_combine<<<(N + 1) / 2, 256, 0, stream>>>(Opart, lpart, cur, ident,
                                                (float*)d_out, N, NP, S);
}

// Round 6
// 341.755 us; speedup vs baseline: 5.8515x; 1.1392x over previous
//
#include <hip/hip_runtime.h>
#include <hip/hip_bf16.h>

typedef unsigned short u16;
typedef unsigned int u32;
typedef __bf16 bf16x8 __attribute__((ext_vector_type(8)));
typedef float f32x4 __attribute__((ext_vector_type(4)));

#define GF_BIAS 1
#define GF_BF16 2
#define GF_TRANS 4

#define MFMA16(a, b, c) __builtin_amdgcn_mfma_f32_16x16x32_bf16(a, b, c, 0, 0, 0)

static __device__ __forceinline__ u16 f2b(float f) {
  u32 u = __float_as_uint(f);
  return (u16)((u + 0x7FFFu + ((u >> 16) & 1u)) >> 16);
}
static __device__ __forceinline__ float blo(u32 u) { return __uint_as_float(u << 16); }
static __device__ __forceinline__ float bhi(u32 u) { return __uint_as_float(u & 0xffff0000u); }

// async 16B/lane global->LDS DMA; dst = uniform base + lane*16
static __device__ __forceinline__ void async_copy16(void* lds, const void* gp) {
  __builtin_amdgcn_global_load_lds(
      (const __attribute__((address_space(1))) unsigned int*)gp,
      (__attribute__((address_space(3))) unsigned int*)lds, 16, 0, 0);
}

// ---------------- CSR build ----------------
__global__ void degi_kernel(const int* __restrict__ dst, int* __restrict__ degi, int E) {
  int e = blockIdx.x * 256 + threadIdx.x;
  if (e < E) atomicAdd(&degi[dst[e]], 1);
}

__global__ void dis_kernel(const int* __restrict__ degi, float* __restrict__ d, int N) {
  int i = blockIdx.x * 256 + threadIdx.x;
  if (i < N) d[i] = rsqrtf((float)degi[i] + 1.0f);  // +1 = self loop
}

__global__ void start_kernel(const int* __restrict__ degi, int* __restrict__ startb,
                             int* __restrict__ counter, int N) {
  int i = blockIdx.x * 256 + threadIdx.x;
  if (i < N) startb[i] = atomicAdd(counter, degi[i]);
}

__global__ void fill_kernel(const int* __restrict__ src, const int* __restrict__ dst,
                            const int* __restrict__ startb, int* __restrict__ cursor,
                            int* __restrict__ adj, int E) {
  int e = blockIdx.x * 256 + threadIdx.x;
  if (e < E) {
    int d = dst[e];
    int p = atomicAdd(&cursor[d], 1);
    adj[startb[d] + p] = src[e];
  }
}

// ---------------- casts ----------------
__global__ void cast_x_kernel(const float* __restrict__ x, u16* __restrict__ xb, int n4) {
  int t = blockIdx.x * 256 + threadIdx.x;
  if (t >= n4) return;
  float4 v = *(const float4*)&x[t * 4];
  ushort4 o;
  o.x = f2b(v.x); o.y = f2b(v.y); o.z = f2b(v.z); o.w = f2b(v.w);
  *(ushort4*)&xb[t * 4] = o;
}

// transpose+cast 6 weights: W[K,128] f32 -> Wt[128,K] bf16, packed contiguous
__global__ void cast_w_kernel(const float* __restrict__ W1, const float* __restrict__ Ws,
                              const float* __restrict__ W2, const float* __restrict__ Wq,
                              const float* __restrict__ Wk, const float* __restrict__ Wv,
                              u16* __restrict__ out) {
  int t = blockIdx.x * 256 + threadIdx.x;
  if (t >= 131072) return;
  const float* src; int K, base, loc;
  if (t < 65536) {
    if (t < 32768) { src = W1; base = 0; } else { src = Ws; base = 32768; }
    loc = t - base; K = 256;
  } else {
    int seg = (t - 65536) >> 14;
    src = (seg == 0) ? W2 : (seg == 1) ? Wq : (seg == 2) ? Wk : Wv;
    base = 65536 + seg * 16384; loc = t & 16383; K = 128;
  }
  int k = loc >> 7, c = loc & 127;          // src is [K,128]: loc = k*128 + c
  out[base + c * K + k] = f2b(src[loc]);    // out is [128,K]
}

// ---------------- bf16 MFMA GEMM: C[M, cb*64..+64] = A[M,K] @ Wt[128,K]^T ----------------
// 1 wave / block, 16 rows x 64 cols; grid.y=2 splits the 128 cols (more waves in flight).
__global__ __launch_bounds__(64) void bgemm(
    const u16* __restrict__ A, const u16* __restrict__ Wt,
    const float* __restrict__ bias, void* __restrict__ Cout,
    int M, int K, int flags, float oscale, int ldt)
{
  int lane = threadIdx.x;
  int col = lane & 15, quad = lane >> 4;
  int row0 = blockIdx.x * 16;
  int cb = blockIdx.y * 64;
  int ar = row0 + col; if (ar > M - 1) ar = M - 1;
  const u16* ap = A + (size_t)ar * K + quad * 8;
  f32x4 O[4];
#pragma unroll
  for (int i = 0; i < 4; i++) { O[i][0] = 0.f; O[i][1] = 0.f; O[i][2] = 0.f; O[i][3] = 0.f; }
  for (int k0 = 0; k0 < K; k0 += 32) {
    bf16x8 aA = *(const bf16x8*)(ap + k0);
#pragma unroll
    for (int nb = 0; nb < 4; nb++) {
      const u16* bp = Wt + (size_t)(cb + nb * 16 + col) * K + k0 + quad * 8;
      O[nb] = MFMA16(aA, *(const bf16x8*)bp, O[nb]);
    }
  }
#pragma unroll
  for (int nb = 0; nb < 4; nb++) {
    int ch = cb + nb * 16 + col;
    float bv = (flags & GF_BIAS) ? bias[ch] : 0.f;
#pragma unroll
    for (int r = 0; r < 4; r++) {
      int row = row0 + quad * 4 + r;
      if (row >= M) continue;
      float v = (O[nb][r] + bv) * oscale;
      if (flags & GF_BF16) {
        u16 hb = f2b(v);
        if (flags & GF_TRANS) ((u16*)Cout)[(size_t)ch * ldt + row] = hb;
        else                  ((u16*)Cout)[(size_t)row * 128 + ch] = hb;
      } else {
        ((float*)Cout)[(size_t)row * 128 + ch] = v;
      }
    }
  }
}

// ---------------- fused CSR gather (bf16 h) + self-loop + bias + LN (+SiLU) ----------------
// Wave per row; lane covers channels (2*lane, 2*lane+1) -> ONE u32 load per neighbor.
__global__ __launch_bounds__(256) void gather_ln(
    const u16* __restrict__ h, const float* __restrict__ dis,
    const int* __restrict__ adj, const int* __restrict__ startb, const int* __restrict__ degi,
    const float* __restrict__ bias, const float* __restrict__ g, const float* __restrict__ beta,
    float* __restrict__ out, u16* __restrict__ outb, int N, int do_silu)
{
  int row = blockIdx.x * 4 + (threadIdx.x >> 6);
  int lane = threadIdx.x & 63;
  if (row >= N) return;
  int st = startb[row], dg = degi[row];
  int c2 = lane * 2;
  float v0 = 0.f, v1 = 0.f;
  for (int base = 0; base < dg; base += 64) {
    int nb = min(64, dg - base);
    int myadj = 0; float mydis = 0.f;
    if (lane < nb) { myadj = adj[st + base + lane]; mydis = dis[myadj]; }
    int jj = 0;
    for (; jj + 4 <= nb; jj += 4) {
      int s0 = __shfl(myadj, jj), s1 = __shfl(myadj, jj + 1);
      int s2 = __shfl(myadj, jj + 2), s3 = __shfl(myadj, jj + 3);
      float w0 = __shfl(mydis, jj), w1 = __shfl(mydis, jj + 1);
      float w2 = __shfl(mydis, jj + 2), w3 = __shfl(mydis, jj + 3);
      u32 a0 = *(const u32*)&h[(size_t)s0 * 128 + c2];
      u32 a1 = *(const u32*)&h[(size_t)s1 * 128 + c2];
      u32 a2 = *(const u32*)&h[(size_t)s2 * 128 + c2];
      u32 a3 = *(const u32*)&h[(size_t)s3 * 128 + c2];
      v0 += w0 * blo(a0); v1 += w0 * bhi(a0);
      v0 += w1 * blo(a1); v1 += w1 * bhi(a1);
      v0 += w2 * blo(a2); v1 += w2 * bhi(a2);
      v0 += w3 * blo(a3); v1 += w3 * bhi(a3);
    }
    for (; jj < nb; jj++) {
      int s = __shfl(myadj, jj);
      float wv = __shfl(mydis, jj);
      u32 a = *(const u32*)&h[(size_t)s * 128 + c2];
      v0 += wv * blo(a); v1 += wv * bhi(a);
    }
  }
  float dd = dis[row];
  u32 aself = *(const u32*)&h[(size_t)row * 128 + c2];
  v0 = (v0 + dd * blo(aself)) * dd + bias[c2];
  v1 = (v1 + dd * bhi(aself)) * dd + bias[c2 + 1];
  float s = v0 + v1;
#pragma unroll
  for (int d = 32; d > 0; d >>= 1) s += __shfl_xor(s, d, 64);
  float mu = s * (1.0f / 128.0f);
  float d0 = v0 - mu, d1 = v1 - mu;
  float q = d0 * d0 + d1 * d1;
#pragma unroll
  for (int d = 32; d > 0; d >>= 1) q += __shfl_xor(q, d, 64);
  float rstd = rsqrtf(q * (1.0f / 128.0f) + 1e-5f);
  float o0 = d0 * rstd * g[c2]     + beta[c2];
  float o1 = d1 * rstd * g[c2 + 1] + beta[c2 + 1];
  if (do_silu) {
    o0 = o0 / (1.f + __expf(-o0));
    o1 = o1 / (1.f + __expf(-o1));
  }
  size_t base = (size_t)row * 128;
  *(float2*)&out[base + c2] = make_float2(o0, o1);
  u32 pk = (u32)f2b(o0) | ((u32)f2b(o1) << 16);
  *(u32*)&outb[base + c2] = pk;
}

// ---------------- flash attention partial: 128-row Q tile (32/wave) x K-chunk ----------------
// Fixed softmax base (scores bounded, no max tracking): P = exp(S) directly, padded
// keys masked to -1e30 -> exp = 0. Writes unnormalized O (bf16) + per-row l.
__global__ __launch_bounds__(256, 3) void flash_part(
    const u16* __restrict__ qb, const u16* __restrict__ kb, const u16* __restrict__ vt,
    u16* __restrict__ Opart, float* __restrict__ lpart,
    int N, int NP, int CHUNK)
{
  __shared__ __align__(16) u16 Kl[64 * 128];   // [key][128ch], swizzled 16B chunks
  __shared__ __align__(16) u16 Vl[128 * 64];   // [ch][64key], swizzled 16B chunks
  __shared__ __align__(16) u16 Pl[4][32][72];  // per-wave P relayout, +8 pad
  int tid = threadIdx.x;
  int w = tid >> 6, lane = tid & 63;
  int col = lane & 15, quad = lane >> 4;
  int h8 = col & 7;
  int ks = blockIdx.y;
  int kstart = ks * CHUNK;
  int qbase = blockIdx.x * 128 + w * 32;

  bf16x8 aQ[2][4];
#pragma unroll
  for (int rg = 0; rg < 2; rg++) {
    int qr = qbase + rg * 16 + col; if (qr > N - 1) qr = N - 1;
    const u16* qp = qb + (size_t)qr * 128 + quad * 8;
    aQ[rg][0] = *(const bf16x8*)(qp);
    aQ[rg][1] = *(const bf16x8*)(qp + 32);
    aQ[rg][2] = *(const bf16x8*)(qp + 64);
    aQ[rg][3] = *(const bf16x8*)(qp + 96);
  }

  f32x4 O[2][8];
#pragma unroll
  for (int rg = 0; rg < 2; rg++)
#pragma unroll
    for (int i = 0; i < 8; i++) { O[rg][i][0] = 0.f; O[rg][i][1] = 0.f; O[rg][i][2] = 0.f; O[rg][i][3] = 0.f; }
  float lr[2][4] = {{0.f, 0.f, 0.f, 0.f}, {0.f, 0.f, 0.f, 0.f}};

  int l16 = lane >> 4, c16 = lane & 15;  // K staging: 4 rows x 16 chunks / instr
  int l8 = lane >> 3,  c8 = lane & 7;    // V staging: 8 rows x 8 chunks / instr

  int KT = (min(CHUNK, NP - kstart)) >> 6;

  for (int kt = 0; kt < KT; kt++) {
    int k0 = kstart + (kt << 6);
    // stage K/V tile
#pragma unroll
    for (int i = 0; i < 4; i++) {
      int rl = w * 16 + i * 4 + l16;
      int cg = c16 ^ (rl & 7);
      async_copy16(&Kl[(w * 16 + i * 4) * 128], kb + (size_t)(k0 + rl) * 128 + cg * 8);
    }
#pragma unroll
    for (int i = 0; i < 4; i++) {
      int ch = w * 32 + i * 8 + l8;
      int cg = c8 ^ (ch & 7);
      async_copy16(&Vl[(w * 32 + i * 8) * 64], vt + (size_t)ch * NP + k0 + cg * 8);
    }
    __syncthreads();  // drains DMA

    bool edge = (k0 + 64 > N);
#pragma unroll
    for (int g = 0; g < 4; g++) {
      const u16* kr = Kl + (g * 16 + col) * 128;
      bf16x8 kf0 = *(const bf16x8*)(kr + (((0 + quad) ^ h8) << 3));
      bf16x8 kf1 = *(const bf16x8*)(kr + (((4 + quad) ^ h8) << 3));
      bf16x8 kf2 = *(const bf16x8*)(kr + (((8 + quad) ^ h8) << 3));
      bf16x8 kf3 = *(const bf16x8*)(kr + (((12 + quad) ^ h8) << 3));
      f32x4 s0; s0[0] = 0.f; s0[1] = 0.f; s0[2] = 0.f; s0[3] = 0.f;
      f32x4 s1 = s0;
      s0 = MFMA16(aQ[0][0], kf0, s0); s1 = MFMA16(aQ[1][0], kf0, s1);
      s0 = MFMA16(aQ[0][1], kf1, s0); s1 = MFMA16(aQ[1][1], kf1, s1);
      s0 = MFMA16(aQ[0][2], kf2, s0); s1 = MFMA16(aQ[1][2], kf2, s1);
      s0 = MFMA16(aQ[0][3], kf3, s0); s1 = MFMA16(aQ[1][3], kf3, s1);
      if (edge && (k0 + g * 16 + col >= N)) {
        s0[0] = -1e30f; s0[1] = -1e30f; s0[2] = -1e30f; s0[3] = -1e30f;
        s1 = s0;
      }
      // P = exp(S); accumulate l per-lane; stash bf16 (RTZ) into LDS for relayout
#pragma unroll
      for (int r = 0; r < 4; r++) {
        float p0 = __expf(s0[r]);
        float p1 = __expf(s1[r]);
        lr[0][r] += p0;
        lr[1][r] += p1;
        Pl[w][quad * 4 + r][g * 16 + col]      = (u16)(__float_as_uint(p0) >> 16);
        Pl[w][16 + quad * 4 + r][g * 16 + col] = (u16)(__float_as_uint(p1) >> 16);
      }
    }
    asm volatile("s_waitcnt lgkmcnt(0)" ::: "memory");
    bf16x8 aP[2][2];
#pragma unroll
    for (int rg = 0; rg < 2; rg++) {
      aP[rg][0] = *(const bf16x8*)&Pl[w][rg * 16 + col][quad * 8];
      aP[rg][1] = *(const bf16x8*)&Pl[w][rg * 16 + col][32 + quad * 8];
    }
    // O += P @ V (V-frags register-reused across both row groups)
#pragma unroll
    for (int nb = 0; nb < 8; nb++) {
      const u16* vr = Vl + (nb * 16 + col) * 64;
      bf16x8 vf0 = *(const bf16x8*)(vr + (((0 + quad) ^ h8) << 3));
      bf16x8 vf1 = *(const bf16x8*)(vr + (((4 + quad) ^ h8) << 3));
      O[0][nb] = MFMA16(aP[0][0], vf0, O[0][nb]);
      O[0][nb] = MFMA16(aP[0][1], vf1, O[0][nb]);
      O[1][nb] = MFMA16(aP[1][0], vf0, O[1][nb]);
      O[1][nb] = MFMA16(aP[1][1], vf1, O[1][nb]);
    }
    __syncthreads();  // protect Kl/Vl before next stage
  }

  // row-sum l across the 16 col lanes (once, at the end)
#pragma unroll
  for (int d = 1; d < 16; d <<= 1) {
#pragma unroll
    for (int rg = 0; rg < 2; rg++)
#pragma unroll
      for (int r = 0; r < 4; r++) lr[rg][r] += __shfl_xor(lr[rg][r], d, 64);
  }

  // write partials
#pragma unroll
  for (int rg = 0; rg < 2; rg++) {
#pragma unroll
    for (int nb = 0; nb < 8; nb++) {
      int ch = nb * 16 + col;
#pragma unroll
      for (int r = 0; r < 4; r++) {
        int row = qbase + rg * 16 + quad * 4 + r;
        if (row < N)
          Opart[((size_t)ks * NP + row) * 128 + ch] = f2b(O[rg][nb][r]);
      }
    }
  }
  if (col == 0) {
#pragma unroll
    for (int rg = 0; rg < 2; rg++)
#pragma unroll
      for (int r = 0; r < 4; r++) {
        int row = qbase + rg * 16 + quad * 4 + r;
        if (row < N) lpart[(size_t)ks * NP + row] = lr[rg][r];
      }
  }
}

// ---------------- combine K-split partials + out2 + identity + SiLU ----------------
__global__ __launch_bounds__(256) void attn_combine(
    const u16* __restrict__ Opart, const float* __restrict__ lpart,
    const float* __restrict__ out2, const float* __restrict__ ident, float* __restrict__ out,
    int N, int NP, int S)
{
  int row = blockIdx.x * 2 + (threadIdx.x >> 7);
  int ch = threadIdx.x & 127;
  if (row >= N) return;
  float num = 0.f, den = 0.f;
  for (int u = 0; u < S; u++) {
    u32 b = Opart[((size_t)u * NP + row) * 128 + ch];
    num += __uint_as_float(b << 16);
    den += lpart[(size_t)u * NP + row];
  }
  size_t idx = (size_t)row * 128 + ch;
  float val = num / den + out2[idx] + ident[idx];
  out[idx] = val / (1.f + __expf(-val));  // silu
}

extern "C" void kernel_launch(void* const* d_in, const int* in_sizes, int n_in,
                              void* d_out, int out_size, void* d_ws, size_t ws_size,
                              hipStream_t stream) {
  const float* x   = (const float*)d_in[0];
  const int*   ei  = (const int*)d_in[1];
  const float* W1  = (const float*)d_in[2];
  const float* b1  = (const float*)d_in[3];
  const float* W2  = (const float*)d_in[4];
  const float* b2  = (const float*)d_in[5];
  const float* g1  = (const float*)d_in[6];
  const float* be1 = (const float*)d_in[7];
  const float* g2  = (const float*)d_in[8];
  const float* be2 = (const float*)d_in[9];
  const float* Wq  = (const float*)d_in[10];
  const float* bq  = (const float*)d_in[11];
  const float* Wk  = (const float*)d_in[12];
  const float* bk  = (const float*)d_in[13];
  const float* Wv  = (const float*)d_in[14];
  const float* bv  = (const float*)d_in[15];
  const float* Wsw = (const float*)d_in[16];
  const float* bs  = (const float*)d_in[17];

  const int CIN = 256, C = 128;
  int N = in_sizes[0] / CIN;
  int E = in_sizes[1] / 2;
  int NP = (N + 63) & ~63;
  const int* src = ei;
  const int* dstp = ei + E;

  const int S = 8;
  int tiles = NP / 64;
  int CHUNK = ((tiles + S - 1) / S) * 64;  // keys per split, mult of 64

  char* w = (char*)d_ws;
  size_t off = 0;
  auto alloc = [&](size_t bytes) -> void* {
    void* p = w + off;
    off = (off + bytes + 255) & ~(size_t)255;
    return p;
  };
  // degi/cursor/counter contiguous -> one memset
  int*   degi   = (int*)alloc((size_t)N * 4);
  int*   cursor = (int*)alloc((size_t)N * 4);
  int*   counter= (int*)alloc(256);
  size_t zlen   = off;
  float* disb   = (float*)alloc((size_t)N * 4);
  int*   startb = (int*)alloc((size_t)N * 4);
  int*   adj    = (int*)alloc((size_t)E * 4);
  u16*   h      = (u16*)alloc((size_t)N * C * 2);   // bf16 h1/h2
  float* ident  = (float*)alloc((size_t)N * C * 4);
  float* cur    = (float*)alloc((size_t)N * C * 4);
  u16*   xb     = (u16*)alloc((size_t)N * CIN * 2);
  u16*   curb   = (u16*)alloc((size_t)N * C * 2);
  u16*   wt     = (u16*)alloc((size_t)131072 * 2);
  u16*   qbb    = (u16*)alloc((size_t)N * C * 2);
  u16*   kbb    = (u16*)alloc((size_t)NP * C * 2);
  u16*   vt     = (u16*)alloc((size_t)C * NP * 2);
  u16*   Opart  = (u16*)alloc((size_t)S * NP * C * 2);
  float* lpart  = (float*)alloc((size_t)S * NP * 4);

  u16* wt1 = wt;            // [128,256]
  u16* wts = wt + 32768;    // [128,256]
  u16* wt2 = wt + 65536;    // [128,128]
  u16* wtq = wt + 81920;
  u16* wtk = wt + 98304;
  u16* wtv = wt + 114688;

  hipMemsetAsync(degi, 0, zlen, stream);

  int gE = (E + 255) / 256, gN = (N + 255) / 256;
  degi_kernel<<<gE, 256, 0, stream>>>(dstp, degi, E);
  dis_kernel<<<gN, 256, 0, stream>>>(degi, disb, N);
  start_kernel<<<gN, 256, 0, stream>>>(degi, startb, counter, N);
  fill_kernel<<<gE, 256, 0, stream>>>(src, dstp, startb, cursor, adj, E);

  int n4 = N * CIN / 4;
  cast_x_kernel<<<(n4 + 255) / 256, 256, 0, stream>>>(x, xb, n4);
  cast_w_kernel<<<512, 256, 0, stream>>>(W1, Wsw, W2, Wq, Wk, Wv, wt);

  dim3 gbg((N + 15) / 16, 2);
  // h1 = x @ W1 -> bf16 (bias folded into gather_ln)
  bgemm<<<gbg, 64, 0, stream>>>(xb, wt1, nullptr, h, N, CIN, GF_BF16, 1.f, 0);
  // identity = x @ Ws + bs (fp32)
  bgemm<<<gbg, 64, 0, stream>>>(xb, wts, bs, ident, N, CIN, GF_BIAS, 1.f, 0);
  // out1 = silu(LN1(gather(h1) + b1))
  gather_ln<<<(N + 3) / 4, 256, 0, stream>>>(h, disb, adj, startb, degi, b1, g1, be1, cur, curb, N, 1);
  // h2 = out1 @ W2 -> bf16
  bgemm<<<gbg, 64, 0, stream>>>(curb, wt2, nullptr, h, N, C, GF_BF16, 1.f, 0);
  // out2 = LN2(gather(h2) + b2)
  gather_ln<<<(N + 3) / 4, 256, 0, stream>>>(h, disb, adj, startb, degi, b2, g2, be2, cur, curb, N, 0);

  const float qscale = 0.08838834764831845f;  // 1/sqrt(128)
  bgemm<<<gbg, 64, 0, stream>>>(curb, wtq, bq, qbb, N, C, GF_BIAS | GF_BF16, qscale, 0);
  bgemm<<<gbg, 64, 0, stream>>>(curb, wtk, bk, kbb, N, C, GF_BIAS | GF_BF16, 1.f, 0);
  bgemm<<<gbg, 64, 0, stream>>>(curb, wtv, bv, vt, N, C, GF_BIAS | GF_BF16 | GF_TRANS, 1.f, NP);

  dim3 fg((N + 127) / 128, S);
  flash_part<<<fg, 256, 0, stream>>>(qbb, kbb, vt, Opart, lpart, N, NP, CHUNK);
  attn_combine<<<(N + 1) / 2, 256, 0, stream>>>(Opart, lpart, cur, ident,
                                                (float*)d_out, N, NP, S);
}

// Round 7
// 293.865 us; speedup vs baseline: 6.8051x; 1.1630x over previous
//
#include <hip/hip_runtime.h>
#include <hip/hip_bf16.h>

typedef unsigned short u16;
typedef unsigned int u32;
typedef __bf16 bf16x8 __attribute__((ext_vector_type(8)));
typedef float f32x4 __attribute__((ext_vector_type(4)));

#define MFMA16(a, b, c) __builtin_amdgcn_mfma_f32_16x16x32_bf16(a, b, c, 0, 0, 0)

static __device__ __forceinline__ u16 f2b(float f) {
  u32 u = __float_as_uint(f);
  return (u16)((u + 0x7FFFu + ((u >> 16) & 1u)) >> 16);
}
static __device__ __forceinline__ float blo(u32 u) { return __uint_as_float(u << 16); }
static __device__ __forceinline__ float bhi(u32 u) { return __uint_as_float(u & 0xffff0000u); }

// async 16B/lane global->LDS DMA; dst = uniform base + lane*16
static __device__ __forceinline__ void async_copy16(void* lds, const void* gp) {
  __builtin_amdgcn_global_load_lds(
      (const __attribute__((address_space(1))) unsigned int*)gp,
      (__attribute__((address_space(3))) unsigned int*)lds, 16, 0, 0);
}

// ---------------- CSR build ----------------
__global__ void degi_kernel(const int* __restrict__ dst, int* __restrict__ degi, int E) {
  int e = blockIdx.x * 256 + threadIdx.x;
  if (e < E) atomicAdd(&degi[dst[e]], 1);
}

__global__ void dis_start_kernel(const int* __restrict__ degi, float* __restrict__ d,
                                 int* __restrict__ startb, int* __restrict__ counter, int N) {
  int i = blockIdx.x * 256 + threadIdx.x;
  if (i < N) {
    int dg = degi[i];
    d[i] = rsqrtf((float)dg + 1.0f);  // +1 = self loop
    startb[i] = atomicAdd(counter, dg);
  }
}

__global__ void fill_kernel(const int* __restrict__ src, const int* __restrict__ dst,
                            const int* __restrict__ startb, int* __restrict__ cursor,
                            int* __restrict__ adj, int E) {
  int e = blockIdx.x * 256 + threadIdx.x;
  if (e < E) {
    int d = dst[e];
    int p = atomicAdd(&cursor[d], 1);
    adj[startb[d] + p] = src[e];
  }
}

// ---------------- fused casts: x -> bf16, 6 weights -> transposed bf16 ----------------
__global__ void cast_all_kernel(const float* __restrict__ x, u16* __restrict__ xb, int n4,
                                const float* __restrict__ W1, const float* __restrict__ Ws,
                                const float* __restrict__ W2, const float* __restrict__ Wq,
                                const float* __restrict__ Wk, const float* __restrict__ Wv,
                                u16* __restrict__ out) {
  int t = blockIdx.x * 256 + threadIdx.x;
  if (t < n4) {
    float4 v = *(const float4*)&x[t * 4];
    ushort4 o;
    o.x = f2b(v.x); o.y = f2b(v.y); o.z = f2b(v.z); o.w = f2b(v.w);
    *(ushort4*)&xb[t * 4] = o;
    return;
  }
  int u = t - n4;
  if (u >= 131072) return;
  const float* src; int K, base, loc;
  if (u < 65536) {
    if (u < 32768) { src = W1; base = 0; } else { src = Ws; base = 32768; }
    loc = u - base; K = 256;
  } else {
    int seg = (u - 65536) >> 14;
    src = (seg == 0) ? W2 : (seg == 1) ? Wq : (seg == 2) ? Wk : Wv;
    base = 65536 + seg * 16384; loc = u & 16383; K = 128;
  }
  int k = loc >> 7, c = loc & 127;          // src [K,128]
  out[base + c * K + k] = f2b(src[loc]);    // out [128,K]
}

// ---------------- fused bf16 MFMA GEMMs (A-frag reuse across outputs) ----------------
// h1 = x@W1 (bf16, no bias) and ident = x@Ws + bs (f32). K=256.
__global__ __launch_bounds__(64) void bgemm_dual(
    const u16* __restrict__ A, const u16* __restrict__ Wa, const u16* __restrict__ Wb,
    const float* __restrict__ bsb, u16* __restrict__ outa, float* __restrict__ outb, int M)
{
  int lane = threadIdx.x;
  int col = lane & 15, quad = lane >> 4;
  int row0 = blockIdx.x * 16;
  int cb = blockIdx.y * 64;
  int ar = row0 + col; if (ar > M - 1) ar = M - 1;
  const u16* ap = A + (size_t)ar * 256 + quad * 8;
  f32x4 Oa[4], Ob[4];
#pragma unroll
  for (int i = 0; i < 4; i++) {
    Oa[i][0] = 0.f; Oa[i][1] = 0.f; Oa[i][2] = 0.f; Oa[i][3] = 0.f;
    Ob[i] = Oa[i];
  }
#pragma unroll
  for (int k0 = 0; k0 < 256; k0 += 32) {
    bf16x8 aA = *(const bf16x8*)(ap + k0);
#pragma unroll
    for (int nb = 0; nb < 4; nb++) {
      size_t wofs = (size_t)(cb + nb * 16 + col) * 256 + k0 + quad * 8;
      Oa[nb] = MFMA16(aA, *(const bf16x8*)(Wa + wofs), Oa[nb]);
      Ob[nb] = MFMA16(aA, *(const bf16x8*)(Wb + wofs), Ob[nb]);
    }
  }
#pragma unroll
  for (int nb = 0; nb < 4; nb++) {
    int ch = cb + nb * 16 + col;
    float bv = bsb[ch];
#pragma unroll
    for (int r = 0; r < 4; r++) {
      int row = row0 + quad * 4 + r;
      if (row >= M) continue;
      outa[(size_t)row * 128 + ch] = f2b(Oa[nb][r]);
      outb[(size_t)row * 128 + ch] = Ob[nb][r] + bv;
    }
  }
}

// h2 = out1 @ W2 (bf16, no bias). K=128.
__global__ __launch_bounds__(64) void bgemm_single(
    const u16* __restrict__ A, const u16* __restrict__ Wt, u16* __restrict__ outa, int M)
{
  int lane = threadIdx.x;
  int col = lane & 15, quad = lane >> 4;
  int row0 = blockIdx.x * 16;
  int cb = blockIdx.y * 64;
  int ar = row0 + col; if (ar > M - 1) ar = M - 1;
  const u16* ap = A + (size_t)ar * 128 + quad * 8;
  f32x4 O[4];
#pragma unroll
  for (int i = 0; i < 4; i++) { O[i][0] = 0.f; O[i][1] = 0.f; O[i][2] = 0.f; O[i][3] = 0.f; }
#pragma unroll
  for (int k0 = 0; k0 < 128; k0 += 32) {
    bf16x8 aA = *(const bf16x8*)(ap + k0);
#pragma unroll
    for (int nb = 0; nb < 4; nb++) {
      O[nb] = MFMA16(aA, *(const bf16x8*)(Wt + (size_t)(cb + nb * 16 + col) * 128 + k0 + quad * 8), O[nb]);
    }
  }
#pragma unroll
  for (int nb = 0; nb < 4; nb++) {
    int ch = cb + nb * 16 + col;
#pragma unroll
    for (int r = 0; r < 4; r++) {
      int row = row0 + quad * 4 + r;
      if (row >= M) continue;
      outa[(size_t)row * 128 + ch] = f2b(O[nb][r]);
    }
  }
}

// Q,K,V = out2 @ {Wq,Wk,Wv} + bias. K=128. q scaled; v transposed (ldt=NP).
__global__ __launch_bounds__(64) void bgemm_qkv(
    const u16* __restrict__ A, const u16* __restrict__ Wqt, const u16* __restrict__ Wkt,
    const u16* __restrict__ Wvt, const float* __restrict__ bq, const float* __restrict__ bk,
    const float* __restrict__ bv, u16* __restrict__ q_out, u16* __restrict__ k_out,
    u16* __restrict__ v_out, int M, int NP, float qscale)
{
  int lane = threadIdx.x;
  int col = lane & 15, quad = lane >> 4;
  int row0 = blockIdx.x * 16;
  int cb = blockIdx.y * 64;
  int ar = row0 + col; if (ar > M - 1) ar = M - 1;
  const u16* ap = A + (size_t)ar * 128 + quad * 8;
  f32x4 Oq[4], Ok[4], Ov[4];
#pragma unroll
  for (int i = 0; i < 4; i++) {
    Oq[i][0] = 0.f; Oq[i][1] = 0.f; Oq[i][2] = 0.f; Oq[i][3] = 0.f;
    Ok[i] = Oq[i]; Ov[i] = Oq[i];
  }
#pragma unroll
  for (int k0 = 0; k0 < 128; k0 += 32) {
    bf16x8 aA = *(const bf16x8*)(ap + k0);
#pragma unroll
    for (int nb = 0; nb < 4; nb++) {
      size_t wofs = (size_t)(cb + nb * 16 + col) * 128 + k0 + quad * 8;
      Oq[nb] = MFMA16(aA, *(const bf16x8*)(Wqt + wofs), Oq[nb]);
      Ok[nb] = MFMA16(aA, *(const bf16x8*)(Wkt + wofs), Ok[nb]);
      Ov[nb] = MFMA16(aA, *(const bf16x8*)(Wvt + wofs), Ov[nb]);
    }
  }
#pragma unroll
  for (int nb = 0; nb < 4; nb++) {
    int ch = cb + nb * 16 + col;
    float bqv = bq[ch], bkv = bk[ch], bvv = bv[ch];
#pragma unroll
    for (int r = 0; r < 4; r++) {
      int row = row0 + quad * 4 + r;
      if (row >= M) continue;
      q_out[(size_t)row * 128 + ch] = f2b((Oq[nb][r] + bqv) * qscale);
      k_out[(size_t)row * 128 + ch] = f2b(Ok[nb][r] + bkv);
      v_out[(size_t)ch * NP + row] = f2b(Ov[nb][r] + bvv);
    }
  }
}

// ---------------- fused CSR gather (bf16 h) + self-loop + bias + LN (+SiLU) ----------------
__global__ __launch_bounds__(256) void gather_ln(
    const u16* __restrict__ h, const float* __restrict__ dis,
    const int* __restrict__ adj, const int* __restrict__ startb, const int* __restrict__ degi,
    const float* __restrict__ bias, const float* __restrict__ g, const float* __restrict__ beta,
    float* __restrict__ out, u16* __restrict__ outb, int N, int do_silu)
{
  int row = blockIdx.x * 4 + (threadIdx.x >> 6);
  int lane = threadIdx.x & 63;
  if (row >= N) return;
  int st = startb[row], dg = degi[row];
  int c2 = lane * 2;
  float v0 = 0.f, v1 = 0.f;
  for (int base = 0; base < dg; base += 64) {
    int nb = min(64, dg - base);
    int myadj = 0; float mydis = 0.f;
    if (lane < nb) { myadj = adj[st + base + lane]; mydis = dis[myadj]; }
    int jj = 0;
    for (; jj + 4 <= nb; jj += 4) {
      int s0 = __shfl(myadj, jj), s1 = __shfl(myadj, jj + 1);
      int s2 = __shfl(myadj, jj + 2), s3 = __shfl(myadj, jj + 3);
      float w0 = __shfl(mydis, jj), w1 = __shfl(mydis, jj + 1);
      float w2 = __shfl(mydis, jj + 2), w3 = __shfl(mydis, jj + 3);
      u32 a0 = *(const u32*)&h[(size_t)s0 * 128 + c2];
      u32 a1 = *(const u32*)&h[(size_t)s1 * 128 + c2];
      u32 a2 = *(const u32*)&h[(size_t)s2 * 128 + c2];
      u32 a3 = *(const u32*)&h[(size_t)s3 * 128 + c2];
      v0 += w0 * blo(a0); v1 += w0 * bhi(a0);
      v0 += w1 * blo(a1); v1 += w1 * bhi(a1);
      v0 += w2 * blo(a2); v1 += w2 * bhi(a2);
      v0 += w3 * blo(a3); v1 += w3 * bhi(a3);
    }
    for (; jj < nb; jj++) {
      int s = __shfl(myadj, jj);
      float wv = __shfl(mydis, jj);
      u32 a = *(const u32*)&h[(size_t)s * 128 + c2];
      v0 += wv * blo(a); v1 += wv * bhi(a);
    }
  }
  float dd = dis[row];
  u32 aself = *(const u32*)&h[(size_t)row * 128 + c2];
  v0 = (v0 + dd * blo(aself)) * dd + bias[c2];
  v1 = (v1 + dd * bhi(aself)) * dd + bias[c2 + 1];
  float s = v0 + v1;
#pragma unroll
  for (int d = 32; d > 0; d >>= 1) s += __shfl_xor(s, d, 64);
  float mu = s * (1.0f / 128.0f);
  float d0 = v0 - mu, d1 = v1 - mu;
  float q = d0 * d0 + d1 * d1;
#pragma unroll
  for (int d = 32; d > 0; d >>= 1) q += __shfl_xor(q, d, 64);
  float rstd = rsqrtf(q * (1.0f / 128.0f) + 1e-5f);
  float o0 = d0 * rstd * g[c2]     + beta[c2];
  float o1 = d1 * rstd * g[c2 + 1] + beta[c2 + 1];
  if (do_silu) {
    o0 = o0 / (1.f + __expf(-o0));
    o1 = o1 / (1.f + __expf(-o1));
  }
  size_t base = (size_t)row * 128;
  *(float2*)&out[base + c2] = make_float2(o0, o1);
  u32 pk = (u32)f2b(o0) | ((u32)f2b(o1) << 16);
  *(u32*)&outb[base + c2] = pk;
}

// ---------------- flash attention partial: 128-row Q tile (32/wave), 32-key tiles ----------------
// Pipelined double-buffer: raw "s_waitcnt vmcnt(0); s_barrier" at loop top, next tile's
// DMA issued BEFORE compute so it overlaps MFMA/LDS work (no full drain between stage+compute).
// Fixed softmax base (no max tracking): P = exp(S); padded keys masked -> exp = 0.
__global__ __launch_bounds__(256, 3) void flash_part(
    const u16* __restrict__ qb, const u16* __restrict__ kb, const u16* __restrict__ vt,
    u16* __restrict__ Opart, float* __restrict__ lpart,
    int N, int NP, int CHUNK)
{
  __shared__ __align__(16) u16 Kl[2][32 * 128];  // [key][128ch], chunk ^= key&7
  __shared__ __align__(16) u16 Vl[2][128 * 32];  // [ch][32key], chunk ^= (ch>>1)&3
  __shared__ __align__(16) u16 Pl[4][32][40];    // per-wave P relayout, stride 40 (16B-aligned, bank-clean)
  int tid = threadIdx.x;
  int w = tid >> 6, lane = tid & 63;
  int col = lane & 15, quad = lane >> 4;
  int h8 = col & 7;
  int ks = blockIdx.y;
  int kstart = ks * CHUNK;
  int qbase = blockIdx.x * 128 + w * 32;

  bf16x8 aQ[2][4];
#pragma unroll
  for (int rg = 0; rg < 2; rg++) {
    int qr = qbase + rg * 16 + col; if (qr > N - 1) qr = N - 1;
    const u16* qp = qb + (size_t)qr * 128 + quad * 8;
    aQ[rg][0] = *(const bf16x8*)(qp);
    aQ[rg][1] = *(const bf16x8*)(qp + 32);
    aQ[rg][2] = *(const bf16x8*)(qp + 64);
    aQ[rg][3] = *(const bf16x8*)(qp + 96);
  }

  f32x4 O[2][8];
#pragma unroll
  for (int rg = 0; rg < 2; rg++)
#pragma unroll
    for (int i = 0; i < 8; i++) { O[rg][i][0] = 0.f; O[rg][i][1] = 0.f; O[rg][i][2] = 0.f; O[rg][i][3] = 0.f; }
  float lr[2][4] = {{0.f, 0.f, 0.f, 0.f}, {0.f, 0.f, 0.f, 0.f}};

  int l16 = lane >> 4, c16 = lane & 15;  // K staging: 4 rows x 16 chunks / instr
  int vch = lane >> 2, vc4 = lane & 3;   // V staging: 16 ch x 4 chunks / instr

  auto stage = [&](int buf, int k0) {
#pragma unroll
    for (int i = 0; i < 2; i++) {
      int rl = w * 8 + i * 4 + l16;
      int cg = c16 ^ (rl & 7);
      async_copy16(&Kl[buf][(w * 8 + i * 4) * 128], kb + (size_t)(k0 + rl) * 128 + cg * 8);
    }
#pragma unroll
    for (int i = 0; i < 2; i++) {
      int ch = w * 32 + i * 16 + vch;
      int cg = vc4 ^ ((ch >> 1) & 3);
      async_copy16(&Vl[buf][(w * 32 + i * 16) * 32], vt + (size_t)ch * NP + k0 + cg * 8);
    }
  };

  int KT = (min(CHUNK, NP - kstart)) >> 5;
  stage(0, kstart);

  for (int kt = 0; kt < KT; kt++) {
    int buf = kt & 1;
    int k0 = kstart + (kt << 5);
    // own tile-kt DMA complete (only own outstanding), then all-waves sync:
    // after barrier, everyone's kt DMA done AND everyone finished reading buf^1 (tile kt-1).
    asm volatile("s_waitcnt vmcnt(0)\n\ts_barrier" ::: "memory");
    if (kt + 1 < KT) stage(buf ^ 1, k0 + 32);  // overlaps compute below

    const u16* Kb = &Kl[buf][0];
    const u16* Vb = &Vl[buf][0];
    bool edge = (k0 + 32 > N);
#pragma unroll
    for (int g = 0; g < 2; g++) {
      const u16* kr = Kb + (g * 16 + col) * 128;
      bf16x8 kf0 = *(const bf16x8*)(kr + (((0 + quad) ^ h8) << 3));
      bf16x8 kf1 = *(const bf16x8*)(kr + (((4 + quad) ^ h8) << 3));
      bf16x8 kf2 = *(const bf16x8*)(kr + (((8 + quad) ^ h8) << 3));
      bf16x8 kf3 = *(const bf16x8*)(kr + (((12 + quad) ^ h8) << 3));
      f32x4 s0; s0[0] = 0.f; s0[1] = 0.f; s0[2] = 0.f; s0[3] = 0.f;
      f32x4 s1 = s0;
      s0 = MFMA16(aQ[0][0], kf0, s0); s1 = MFMA16(aQ[1][0], kf0, s1);
      s0 = MFMA16(aQ[0][1], kf1, s0); s1 = MFMA16(aQ[1][1], kf1, s1);
      s0 = MFMA16(aQ[0][2], kf2, s0); s1 = MFMA16(aQ[1][2], kf2, s1);
      s0 = MFMA16(aQ[0][3], kf3, s0); s1 = MFMA16(aQ[1][3], kf3, s1);
      if (edge && (k0 + g * 16 + col >= N)) {
        s0[0] = -1e30f; s0[1] = -1e30f; s0[2] = -1e30f; s0[3] = -1e30f;
        s1 = s0;
      }
#pragma unroll
      for (int r = 0; r < 4; r++) {
        float p0 = __expf(s0[r]);
        float p1 = __expf(s1[r]);
        lr[0][r] += p0;
        lr[1][r] += p1;
        Pl[w][quad * 4 + r][g * 16 + col]      = (u16)(__float_as_uint(p0) >> 16);
        Pl[w][16 + quad * 4 + r][g * 16 + col] = (u16)(__float_as_uint(p1) >> 16);
      }
    }
    asm volatile("s_waitcnt lgkmcnt(0)" ::: "memory");
    bf16x8 aP0 = *(const bf16x8*)&Pl[w][col][quad * 8];
    bf16x8 aP1 = *(const bf16x8*)&Pl[w][16 + col][quad * 8];
    // O += P @ V (32-key tile = exactly one MFMA K-depth)
#pragma unroll
    for (int nb = 0; nb < 8; nb++) {
      int ch = nb * 16 + col;
      const u16* vr = Vb + ch * 32;
      bf16x8 vf = *(const bf16x8*)(vr + ((quad ^ ((ch >> 1) & 3)) << 3));
      O[0][nb] = MFMA16(aP0, vf, O[0][nb]);
      O[1][nb] = MFMA16(aP1, vf, O[1][nb]);
    }
  }

  // row-sum l across the 16 col lanes (once, at the end)
#pragma unroll
  for (int d = 1; d < 16; d <<= 1) {
#pragma unroll
    for (int rg = 0; rg < 2; rg++)
#pragma unroll
      for (int r = 0; r < 4; r++) lr[rg][r] += __shfl_xor(lr[rg][r], d, 64);
  }

  // write partials
#pragma unroll
  for (int rg = 0; rg < 2; rg++) {
#pragma unroll
    for (int nb = 0; nb < 8; nb++) {
      int ch = nb * 16 + col;
#pragma unroll
      for (int r = 0; r < 4; r++) {
        int row = qbase + rg * 16 + quad * 4 + r;
        if (row < N)
          Opart[((size_t)ks * NP + row) * 128 + ch] = f2b(O[rg][nb][r]);
      }
    }
  }
  if (col == 0) {
#pragma unroll
    for (int rg = 0; rg < 2; rg++)
#pragma unroll
      for (int r = 0; r < 4; r++) {
        int row = qbase + rg * 16 + quad * 4 + r;
        if (row < N) lpart[(size_t)ks * NP + row] = lr[rg][r];
      }
  }
}

// ---------------- combine K-split partials + out2 + identity + SiLU ----------------
__global__ __launch_bounds__(256) void attn_combine(
    const u16* __restrict__ Opart, const float* __restrict__ lpart,
    const float* __restrict__ out2, const float* __restrict__ ident, float* __restrict__ out,
    int N, int NP, int S)
{
  int row = blockIdx.x * 2 + (threadIdx.x >> 7);
  int ch = threadIdx.x & 127;
  if (row >= N) return;
  float num = 0.f, den = 0.f;
  for (int u = 0; u < S; u++) {
    u32 b = Opart[((size_t)u * NP + row) * 128 + ch];
    num += __uint_as_float(b << 16);
    den += lpart[(size_t)u * NP + row];
  }
  size_t idx = (size_t)row * 128 + ch;
  float val = num / den + out2[idx] + ident[idx];
  out[idx] = val / (1.f + __expf(-val));  // silu
}

extern "C" void kernel_launch(void* const* d_in, const int* in_sizes, int n_in,
                              void* d_out, int out_size, void* d_ws, size_t ws_size,
                              hipStream_t stream) {
  const float* x   = (const float*)d_in[0];
  const int*   ei  = (const int*)d_in[1];
  const float* W1  = (const float*)d_in[2];
  const float* b1  = (const float*)d_in[3];
  const float* W2  = (const float*)d_in[4];
  const float* b2  = (const float*)d_in[5];
  const float* g1  = (const float*)d_in[6];
  const float* be1 = (const float*)d_in[7];
  const float* g2  = (const float*)d_in[8];
  const float* be2 = (const float*)d_in[9];
  const float* Wq  = (const float*)d_in[10];
  const float* bq  = (const float*)d_in[11];
  const float* Wk  = (const float*)d_in[12];
  const float* bk  = (const float*)d_in[13];
  const float* Wv  = (const float*)d_in[14];
  const float* bv  = (const float*)d_in[15];
  const float* Wsw = (const float*)d_in[16];
  const float* bs  = (const float*)d_in[17];

  const int CIN = 256, C = 128;
  int N = in_sizes[0] / CIN;
  int E = in_sizes[1] / 2;
  int NP = (N + 63) & ~63;
  const int* src = ei;
  const int* dstp = ei + E;

  const int S = 8;
  int tiles = NP / 64;
  int CHUNK = ((tiles + S - 1) / S) * 64;  // keys per split, mult of 64 (and of 32)

  char* w = (char*)d_ws;
  size_t off = 0;
  auto alloc = [&](size_t bytes) -> void* {
    void* p = w + off;
    off = (off + bytes + 255) & ~(size_t)255;
    return p;
  };
  // degi/cursor/counter contiguous -> one memset
  int*   degi   = (int*)alloc((size_t)N * 4);
  int*   cursor = (int*)alloc((size_t)N * 4);
  int*   counter= (int*)alloc(256);
  size_t zlen   = off;
  float* disb   = (float*)alloc((size_t)N * 4);
  int*   startb = (int*)alloc((size_t)N * 4);
  int*   adj    = (int*)alloc((size_t)E * 4);
  u16*   h      = (u16*)alloc((size_t)N * C * 2);   // bf16 h1/h2
  float* ident  = (float*)alloc((size_t)N * C * 4);
  float* cur    = (float*)alloc((size_t)N * C * 4);
  u16*   xb     = (u16*)alloc((size_t)N * CIN * 2);
  u16*   curb   = (u16*)alloc((size_t)N * C * 2);
  u16*   wt     = (u16*)alloc((size_t)131072 * 2);
  u16*   qbb    = (u16*)alloc((size_t)N * C * 2);
  u16*   kbb    = (u16*)alloc((size_t)NP * C * 2);
  u16*   vt     = (u16*)alloc((size_t)C * NP * 2);
  u16*   Opart  = (u16*)alloc((size_t)S * NP * C * 2);
  float* lpart  = (float*)alloc((size_t)S * NP * 4);

  u16* wt1 = wt;            // [128,256]
  u16* wts = wt + 32768;    // [128,256]
  u16* wt2 = wt + 65536;    // [128,128]
  u16* wtq = wt + 81920;
  u16* wtk = wt + 98304;
  u16* wtv = wt + 114688;

  hipMemsetAsync(degi, 0, zlen, stream);

  int gE = (E + 255) / 256, gN = (N + 255) / 256;
  degi_kernel<<<gE, 256, 0, stream>>>(dstp, degi, E);
  dis_start_kernel<<<gN, 256, 0, stream>>>(degi, disb, startb, counter, N);
  fill_kernel<<<gE, 256, 0, stream>>>(src, dstp, startb, cursor, adj, E);

  int n4 = N * CIN / 4;
  int ctot = n4 + 131072;
  cast_all_kernel<<<(ctot + 255) / 256, 256, 0, stream>>>(x, xb, n4, W1, Wsw, W2, Wq, Wk, Wv, wt);

  dim3 gbg((N + 15) / 16, 2);
  // h1 = x@W1 -> bf16 ; ident = x@Ws + bs -> f32 (A-frags shared)
  bgemm_dual<<<gbg, 64, 0, stream>>>(xb, wt1, wts, bs, h, ident, N);
  // out1 = silu(LN1(gather(h1) + b1))
  gather_ln<<<(N + 3) / 4, 256, 0, stream>>>(h, disb, adj, startb, degi, b1, g1, be1, cur, curb, N, 1);
  // h2 = out1 @ W2 -> bf16
  bgemm_single<<<gbg, 64, 0, stream>>>(curb, wt2, h, N);
  // out2 = LN2(gather(h2) + b2)
  gather_ln<<<(N + 3) / 4, 256, 0, stream>>>(h, disb, adj, startb, degi, b2, g2, be2, cur, curb, N, 0);

  const float qscale = 0.08838834764831845f;  // 1/sqrt(128)
  bgemm_qkv<<<gbg, 64, 0, stream>>>(curb, wtq, wtk, wtv, bq, bk, bv, qbb, kbb, vt, N, NP, qscale);

  dim3 fg((N + 127) / 128, S);
  flash_part<<<fg, 256, 0, stream>>>(qbb, kbb, vt, Opart, lpart, N, NP, CHUNK);
  attn_combine<<<(N + 1) / 2, 256, 0, stream>>>(Opart, lpart, cur, ident,
                                                (float*)d_out, N, NP, S);
}